// Round 14
// baseline (836.202 us; speedup 1.0000x reference)
//
#include <hip/hip_runtime.h>
#include <hip/hip_bf16.h>
#include <math.h>

#define NF 128
#define EC 50
#define ET 64              // edges per MFMA tile/pass
#define SCH 2048           // scan chunk size
#define CUTOFF 0.8f
#define PI_F 3.14159265358979323846f

typedef __attribute__((ext_vector_type(8))) _Float16 f16x8;
typedef __attribute__((ext_vector_type(2))) _Float16 f16x2;
typedef __attribute__((ext_vector_type(4))) float f32x4;

__device__ __forceinline__ float4 ld4(const float* p) { return *reinterpret_cast<const float4*>(p); }
__device__ __forceinline__ void st4(float* p, float4 v) { *reinterpret_cast<float4*>(p) = v; }

__device__ __forceinline__ float4 f4fma(float a, float4 w, float4 acc) {
    acc.x = fmaf(a, w.x, acc.x); acc.y = fmaf(a, w.y, acc.y);
    acc.z = fmaf(a, w.z, acc.z); acc.w = fmaf(a, w.w, acc.w);
    return acc;
}

// fast ssp: hardware exp/log; validated R7-R13 (absmax 0.0078)
__device__ __forceinline__ float sspf(float x) {
    return fmaxf(x, 0.0f) + __logf(1.0f + __expf(-fabsf(x))) - 0.69314718055994530942f;
}
__device__ __forceinline__ float4 ssp4(float4 v) {
    v.x = sspf(v.x); v.y = sspf(v.y); v.z = sspf(v.z); v.w = sspf(v.w);
    return v;
}
__device__ __forceinline__ float swishf(float x) {
    return x / (1.0f + __expf(-x));
}

// -------------------------------------------------------------------------
__global__ __launch_bounds__(256) void emb_kernel(const float* __restrict__ tt,
                                                  float* __restrict__ emb, int n) {
    int i = blockIdx.x * blockDim.x + threadIdx.x;
    if (i >= n * 64) return;
    int node = i >> 6, k = i & 63;
    float t = tt[node];
    float coef = __expf((float)k * (-6.9077552789821368f / 63.0f));
    float e = t * coef;
    emb[node * NF + k]      = swishf(__sinf(e));
    emb[node * NF + 64 + k] = swishf(__cosf(e));
}

// -------------------------------------------------------------------------
// out[N,128] = f(A[N,128] @ W[128,128] (+bias) (+extra))  — R7-proven version
template<int MODE>
__global__ __launch_bounds__(256) void node_gemm(const float* A,
                                                 const float* __restrict__ W,
                                                 const float* __restrict__ bias,
                                                 const float* extra,
                                                 float* out, int n) {
    extern __shared__ float sm[];
    float* W_lds = sm;            // 128*128
    float* A_lds = sm + NF * NF;  // 32*128
    const int tid = threadIdx.x;
    const int cg = tid & 31;
    const int rg = tid >> 5;

    for (int idx = tid * 4; idx < NF * NF; idx += 1024)
        st4(W_lds + idx, ld4(W + idx));

    float4 bv = make_float4(0.f, 0.f, 0.f, 0.f);
    if (MODE != 0) bv = ld4(bias + 4 * cg);

    const int ntile = (n + 31) >> 5;
    for (int tile = blockIdx.x; tile < ntile; tile += gridDim.x) {
        const int base = tile << 5;
        __syncthreads();
        for (int idx = tid * 4; idx < 32 * NF; idx += 1024) {
            int r = idx >> 7;
            int row = base + r;
            float4 v = make_float4(0.f, 0.f, 0.f, 0.f);
            if (row < n) v = ld4(A + row * NF + (idx & 127));
            st4(A_lds + idx, v);
        }
        __syncthreads();

        float4 acc[4] = {bv, bv, bv, bv};
        #pragma unroll 8
        for (int k4 = 0; k4 < 32; k4++) {
            float4 w0 = ld4(W_lds + (4 * k4 + 0) * NF + 4 * cg);
            float4 w1 = ld4(W_lds + (4 * k4 + 1) * NF + 4 * cg);
            float4 w2 = ld4(W_lds + (4 * k4 + 2) * NF + 4 * cg);
            float4 w3 = ld4(W_lds + (4 * k4 + 3) * NF + 4 * cg);
            #pragma unroll
            for (int rr = 0; rr < 4; rr++) {
                float4 a = ld4(A_lds + (rg * 4 + rr) * NF + 4 * k4);
                acc[rr] = f4fma(a.x, w0, acc[rr]);
                acc[rr] = f4fma(a.y, w1, acc[rr]);
                acc[rr] = f4fma(a.z, w2, acc[rr]);
                acc[rr] = f4fma(a.w, w3, acc[rr]);
            }
        }
        #pragma unroll
        for (int rr = 0; rr < 4; rr++) {
            int row = base + rg * 4 + rr;
            if (row >= n) continue;
            float4 v = acc[rr];
            if (MODE == 2) {
                float4 e4 = ld4(extra + row * NF + 4 * cg);
                v.x += e4.x; v.y += e4.y; v.z += e4.z; v.w += e4.w;
            }
            if (MODE == 1 || MODE == 2) v = ssp4(v);
            st4(out + row * NF + 4 * cg, v);
        }
    }
}

// -------------------------------------------------------------------------
// CSR build: degree -> 3-phase multi-block exclusive scan -> scatter.
__global__ __launch_bounds__(256) void deg_kernel(const int* __restrict__ ei,
                                                  int* __restrict__ deg, int E_) {
    int e = blockIdx.x * blockDim.x + threadIdx.x;
    if (e < E_) atomicAdd(&deg[ei[E_ + e]], 1);
}

// phase 1: per-chunk sums (one block per SCH-element chunk)
__global__ __launch_bounds__(256) void scan_chunk(const int* __restrict__ deg,
                                                  int* __restrict__ csum, int n) {
    int base = blockIdx.x * SCH;
    int s = 0;
    for (int i = threadIdx.x; i < SCH; i += 256) {
        int idx = base + i;
        if (idx < n) s += deg[idx];
    }
    __shared__ int red[4];
    #pragma unroll
    for (int d = 1; d < 64; d <<= 1) s += __shfl_xor(s, d);
    if ((threadIdx.x & 63) == 0) red[threadIdx.x >> 6] = s;
    __syncthreads();
    if (threadIdx.x == 0) csum[blockIdx.x] = red[0] + red[1] + red[2] + red[3];
}

// phase 2: exclusive scan of chunk sums (nch <= 1024); also off[n] = E (known)
__global__ __launch_bounds__(1024) void scan_csum_k(const int* __restrict__ csum,
                                                    int* __restrict__ coff, int nch,
                                                    int* __restrict__ off, int n, int E_) {
    __shared__ int sm[1024];
    const int tid = threadIdx.x;
    int v = (tid < nch) ? csum[tid] : 0;
    sm[tid] = v;
    __syncthreads();
    for (int st = 1; st < 1024; st <<= 1) {
        int t = (tid >= st) ? sm[tid - st] : 0;
        __syncthreads();
        sm[tid] += t;
        __syncthreads();
    }
    if (tid < nch) coff[tid] = sm[tid] - v;   // exclusive
    if (tid == 0) off[n] = E_;                // total degree == E
}

// phase 3: per-chunk local exclusive scan + chunk offset -> off
__global__ __launch_bounds__(256) void scan_emit(const int* __restrict__ deg,
                                                 const int* __restrict__ coff,
                                                 int* __restrict__ off, int n) {
    const int base = blockIdx.x * SCH + threadIdx.x * 8;
    int vals[8]; int s = 0;
    #pragma unroll
    for (int j = 0; j < 8; j++) {
        int idx = base + j;
        vals[j] = (idx < n) ? deg[idx] : 0;
        s += vals[j];
    }
    __shared__ int ts[256];
    ts[threadIdx.x] = s;
    __syncthreads();
    for (int st = 1; st < 256; st <<= 1) {
        int t = (threadIdx.x >= st) ? ts[threadIdx.x - st] : 0;
        __syncthreads();
        ts[threadIdx.x] += t;
        __syncthreads();
    }
    int prefix = coff[blockIdx.x] + ts[threadIdx.x] - s;
    #pragma unroll
    for (int j = 0; j < 8; j++) {
        int idx = base + j;
        if (idx < n) off[idx] = prefix;
        prefix += vals[j];
    }
}

__global__ __launch_bounds__(256) void scatter_kernel(const int* __restrict__ ei,
                                                      const float* __restrict__ elen,
                                                      const int* __restrict__ off,
                                                      int* __restrict__ cur,
                                                      int* __restrict__ perm,
                                                      int* __restrict__ srcp,
                                                      float* __restrict__ Cp, int E_) {
    int e = blockIdx.x * blockDim.x + threadIdx.x;
    if (e < E_) {
        int d = ei[E_ + e];
        int p = off[d] + atomicAdd(&cur[d], 1);
        perm[p] = e;
        srcp[p] = ei[e];
        float len = elen[e];
        float c = 0.5f * (__cosf(len * (PI_F / CUTOFF)) + 1.0f);
        Cp[p] = (len <= CUTOFF && len >= 0.0f) ? c : 0.0f;
    }
}

// tnlo[t] = first node n with off[n] >= 64*t (tile ownership table)
__global__ __launch_bounds__(256) void tilebnd_kernel(const int* __restrict__ off,
                                                      int* __restrict__ tnlo,
                                                      int nN, int ntiles) {
    int t = blockIdx.x * blockDim.x + threadIdx.x;
    if (t > ntiles) return;
    if (t == ntiles) { tnlo[t] = nN; return; }
    int key = t * ET;
    int lo = 0, hi = nN + 1;
    while (lo < hi) { int mid = (lo + hi) >> 1; if (off[mid] < key) lo = mid + 1; else hi = mid; }
    tnlo[t] = lo;
}

// -------------------------------------------------------------------------
// FAST PATH kernel 1: wf_kernel — dense 64-edge MFMA tiles, writes
// msg = Wf*C (fp16, CSR order) to global. Conv-invariant: run ONCE.
// (256,4): cap 128 >= true need ~116 (84 VGPR + 32 AGPR acc) -> no spill,
// 4 waves/SIMD vs 3. ((256,5) cap 102 < 116 would spill — don't.)
__global__ __launch_bounds__(256, 4) void wf_kernel(const float* __restrict__ eattr,
                                                    const float* __restrict__ em1w,
                                                    const float* __restrict__ em1b,
                                                    const float* __restrict__ em2w,
                                                    const float* __restrict__ em2b,
                                                    const int* __restrict__ perm,
                                                    const float* __restrict__ Cp,
                                                    unsigned int* __restrict__ wmsg32,
                                                    int E_) {
    __shared__ __align__(16) char U[ET * 128 + ET * 256];
    __shared__ float C_sm[ET];
    char* ea_p  = U;
    char* h_p   = U + ET * 128;
    char* msg_b = U;               // [64] rows x 264B (132 fp16), overlays ea/h

    const int tid  = threadIdx.x;
    const int wid  = tid >> 6;
    const int lane = tid & 63;
    const int l15  = lane & 15;
    const int lhi  = lane >> 4;

    f16x8 w1f[2][2];
    f16x8 w2f[2][4];
    float b1c[2], b2c[2];
    #pragma unroll
    for (int ct = 0; ct < 2; ct++) {
        const int col = (2 * wid + ct) * 16 + l15;
        b1c[ct] = em1b[col];
        b2c[ct] = em2b[col];
        #pragma unroll
        for (int t = 0; t < 2; t++)
            #pragma unroll
            for (int j = 0; j < 8; j++) {
                int k = t * 32 + lhi * 8 + j;
                w1f[ct][t][j] = (_Float16)((k < EC) ? em1w[k * NF + col] : 0.0f);
            }
        #pragma unroll
        for (int t = 0; t < 4; t++)
            #pragma unroll
            for (int j = 0; j < 8; j++) {
                int k = t * 32 + lhi * 8 + j;
                w2f[ct][t][j] = (_Float16)em2w[k * NF + col];
            }
    }

    const int ntiles = (E_ + ET - 1) / ET;
    for (int tile = blockIdx.x; tile < ntiles; tile += gridDim.x) {
        const int base = tile * ET;
        const int ec = min(ET, E_ - base);
        const int mmax = (ec + 15) >> 4;
        __syncthreads();   // prev copy done

        if (tid < ET) C_sm[tid] = (tid < ec) ? Cp[base + tid] : 0.0f;
        {
            int row = tid >> 2, part = tid & 3;
            bool val = row < ec;
            const float* ep = eattr + (size_t)(val ? perm[base + row] : 0) * EC;
            #pragma unroll
            for (int kk = 0; kk < 16; kk += 2) {
                int k = part * 16 + kk;
                float2 v = make_float2(0.f, 0.f);
                if (val && k <= 48) v = *(const float2*)(ep + k);
                f16x2 pk;
                pk[0] = (_Float16)v.x; pk[1] = (_Float16)v.y;
                *(f16x2*)(ea_p + row * 128 + ((2 * k) ^ ((row & 7) << 4))) = pk;
            }
        }
        __syncthreads();

        // layer 1
        f32x4 acc[4][2];
        #pragma unroll
        for (int m = 0; m < 4; m++) {
            if (m < mmax) {
                #pragma unroll
                for (int ct = 0; ct < 2; ct++) {
                    f32x4 b = {b1c[ct], b1c[ct], b1c[ct], b1c[ct]};
                    acc[m][ct] = b;
                }
                const int row = m * 16 + l15;
                #pragma unroll
                for (int t1 = 0; t1 < 2; t1++) {
                    int o = row * 128 + ((t1 * 64 + lhi * 16) ^ ((row & 7) << 4));
                    f16x8 a = *(const f16x8*)(ea_p + o);
                    #pragma unroll
                    for (int ct = 0; ct < 2; ct++)
                        acc[m][ct] = __builtin_amdgcn_mfma_f32_16x16x32_f16(a, w1f[ct][t1], acc[m][ct], 0, 0, 0);
                }
            }
        }
        #pragma unroll
        for (int m = 0; m < 4; m++) {
            if (m < mmax) {
                #pragma unroll
                for (int ct = 0; ct < 2; ct++) {
                    const int col = (2 * wid + ct) * 16 + l15;
                    #pragma unroll
                    for (int r = 0; r < 4; r++) {
                        int row = m * 16 + lhi * 4 + r;
                        *(_Float16*)(h_p + row * 256 + ((2 * col) ^ ((row & 7) << 4))) =
                            (_Float16)sspf(acc[m][ct][r]);
                    }
                }
            }
        }
        __syncthreads();

        // layer 2
        #pragma unroll
        for (int m = 0; m < 4; m++) {
            if (m < mmax) {
                #pragma unroll
                for (int ct = 0; ct < 2; ct++) {
                    f32x4 b = {b2c[ct], b2c[ct], b2c[ct], b2c[ct]};
                    acc[m][ct] = b;
                }
                const int row = m * 16 + l15;
                #pragma unroll
                for (int t2 = 0; t2 < 4; t2++) {
                    int o = row * 256 + ((t2 * 64 + lhi * 16) ^ ((row & 7) << 4));
                    f16x8 a = *(const f16x8*)(h_p + o);
                    #pragma unroll
                    for (int ct = 0; ct < 2; ct++)
                        acc[m][ct] = __builtin_amdgcn_mfma_f32_16x16x32_f16(a, w2f[ct][t2], acc[m][ct], 0, 0, 0);
                }
            }
        }
        __syncthreads();   // h reads done; msg overlays ea/h

        #pragma unroll
        for (int m = 0; m < 4; m++) {
            if (m < mmax) {
                #pragma unroll
                for (int ct = 0; ct < 2; ct++) {
                    #pragma unroll
                    for (int r = 0; r < 4; r++) {
                        int e = m * 16 + lhi * 4 + r;
                        int ch = (2 * wid + ct) * 16 + l15;
                        *(_Float16*)(msg_b + e * 264 + 2 * ch) =
                            (_Float16)(acc[m][ct][r] * C_sm[e]);
                    }
                }
            }
        }
        __syncthreads();

        // coalesced LDS -> global copy: wmsg[base+e][ch], u32 = 2 fp16
        for (int j = tid; j < ec * 64; j += 256)
            wmsg32[(size_t)base * 64 + j] =
                *(const unsigned int*)(msg_b + (j >> 6) * 264 + (j & 63) * 4);
    }
}

// -------------------------------------------------------------------------
// FAST PATH kernel 2: red_conv — pure gather-reduce, no LDS, no barriers.
// 4-deep load batching (named regs, static indexing) for memory-level
// parallelism on the wmsg stream + y gather.
__global__ __launch_bounds__(256) void red_conv(const float* __restrict__ y,
                                                const _Float16* __restrict__ wmsg,
                                                const int* __restrict__ srcp,
                                                const int* __restrict__ off,
                                                const int* __restrict__ tnlo,
                                                float* __restrict__ agg,
                                                int ntiles) {
    const int wid  = threadIdx.x >> 6;
    const int lane = threadIdx.x & 63;
    const int c2   = lane * 2;

    for (int tile = blockIdx.x; tile < ntiles; tile += gridDim.x) {
        const int n_lo = tnlo[tile], n_hi1 = tnlo[tile + 1];
        for (int n = n_lo + wid; n < n_hi1; n += 4) {
            float2 a = make_float2(0.f, 0.f);
            int i = off[n];
            const int e1 = off[n + 1];
            for (; i + 4 <= e1; i += 4) {
                int s0 = srcp[i], s1 = srcp[i + 1], s2 = srcp[i + 2], s3 = srcp[i + 3];
                f16x2 m0 = *(const f16x2*)(wmsg + (size_t)(i    ) * NF + c2);
                f16x2 m1 = *(const f16x2*)(wmsg + (size_t)(i + 1) * NF + c2);
                f16x2 m2 = *(const f16x2*)(wmsg + (size_t)(i + 2) * NF + c2);
                f16x2 m3 = *(const f16x2*)(wmsg + (size_t)(i + 3) * NF + c2);
                float2 y0 = *(const float2*)(y + (size_t)s0 * NF + c2);
                float2 y1 = *(const float2*)(y + (size_t)s1 * NF + c2);
                float2 y2 = *(const float2*)(y + (size_t)s2 * NF + c2);
                float2 y3 = *(const float2*)(y + (size_t)s3 * NF + c2);
                a.x = fmaf((float)m0[0], y0.x, a.x); a.y = fmaf((float)m0[1], y0.y, a.y);
                a.x = fmaf((float)m1[0], y1.x, a.x); a.y = fmaf((float)m1[1], y1.y, a.y);
                a.x = fmaf((float)m2[0], y2.x, a.x); a.y = fmaf((float)m2[1], y2.y, a.y);
                a.x = fmaf((float)m3[0], y3.x, a.x); a.y = fmaf((float)m3[1], y3.y, a.y);
            }
            for (; i < e1; i++) {
                f16x2 mp = *(const f16x2*)(wmsg + (size_t)i * NF + c2);
                float2 yv = *(const float2*)(y + (size_t)srcp[i] * NF + c2);
                a.x = fmaf((float)mp[0], yv.x, a.x);
                a.y = fmaf((float)mp[1], yv.y, a.y);
            }
            *(float2*)(agg + (size_t)n * NF + c2) = a;
        }
    }
}

// -------------------------------------------------------------------------
extern "C" void kernel_launch(void* const* d_in, const int* in_sizes, int n_in,
                              void* d_out, int out_size, void* d_ws, size_t ws_size,
                              hipStream_t stream) {
    const float* tt    = (const float*)d_in[0];
    const float* xx    = (const float*)d_in[1];
    const int*   ei    = (const int*)d_in[2];
    const float* elen  = (const float*)d_in[3];
    const float* eattr = (const float*)d_in[4];
    const float* em1w  = (const float*)d_in[5];
    const float* em1b  = (const float*)d_in[6];
    const float* em2w  = (const float*)d_in[7];
    const float* em2b  = (const float*)d_in[8];
    const float* c1m1w = (const float*)d_in[9];
    const float* c1m2w = (const float*)d_in[10];
    const float* c1m2b = (const float*)d_in[11];
    const float* c2m1w = (const float*)d_in[12];
    const float* c2m2w = (const float*)d_in[13];
    const float* c2m2b = (const float*)d_in[14];
    const float* tew   = (const float*)d_in[15];
    const float* teb   = (const float*)d_in[16];
    const float* linw  = (const float*)d_in[17];
    const float* linb  = (const float*)d_in[18];

    const int n  = in_sizes[0];
    const int E_ = in_sizes[2] / 2;
    const int ntiles = (E_ + ET - 1) / ET;
    const int nch = (n + SCH - 1) / SCH;      // scan chunks (25 @ n=50k)
    float* out = (float*)d_out;

    const size_t NB = (size_t)n * NF;
    float* B0 = (float*)d_ws;   // y1 / y2 / x3
    float* B1 = B0 + NB;        // agg
    float* B2 = B1 + NB;        // emb -> t (in-place) -> x_mid
    int* off  = (int*)(B2 + NB);      // n+1
    int* perm = off + (n + 1);        // E
    int* deg  = perm + E_;            // n
    int* cur  = deg + n;              // n (deg+cur contiguous for memset)
    int* srcp = cur + n;              // E
    int* tnlo = srcp + E_;            // ntiles+1
    int* csum = tnlo + ntiles + 1;    // nch
    int* coff = csum + nch;           // nch
    float* Cp = (float*)(coff + nch); // E
    _Float16* wmsg = (_Float16*)(Cp + E_);    // E*128 fp16

    const size_t gemm_shmem = (size_t)(NF * NF + 32 * NF) * sizeof(float);   // 80 KB

    // ---- CSR build (multi-block scan) + ownership table
    hipMemsetAsync(deg, 0, (size_t)2 * n * sizeof(int), stream);
    deg_kernel<<<(E_ + 255) / 256, 256, 0, stream>>>(ei, deg, E_);
    scan_chunk<<<nch, 256, 0, stream>>>(deg, csum, n);
    scan_csum_k<<<1, 1024, 0, stream>>>(csum, coff, nch, off, n, E_);
    scan_emit<<<nch, 256, 0, stream>>>(deg, coff, off, n);
    scatter_kernel<<<(E_ + 255) / 256, 256, 0, stream>>>(ei, elen, off, cur,
                                                         perm, srcp, Cp, E_);
    tilebnd_kernel<<<(ntiles + 256) / 256, 256, 0, stream>>>(off, tnlo, n, ntiles);

    // emb -> B2 ; t = swish_emb @ te_w + te_b -> B2 (in-place safe)
    emb_kernel<<<(n * 64 + 255) / 256, 256, 0, stream>>>(tt, B2, n);
    node_gemm<3><<<512, 256, gemm_shmem, stream>>>(B2, tew, teb, nullptr, B2, n);

    // msg = Wf*C (conv-invariant) computed ONCE
    wf_kernel<<<2048, 256, 0, stream>>>(eattr, em1w, em1b, em2w, em2b,
                                        perm, Cp, (unsigned int*)wmsg, E_);

    // y1 = xx @ c1_m1w -> B0
    node_gemm<0><<<512, 256, gemm_shmem, stream>>>(xx, c1m1w, nullptr, nullptr, B0, n);

    // conv1 -> B1
    red_conv<<<2048, 256, 0, stream>>>(B0, wmsg, srcp, off, tnlo, B1, ntiles);

    // x_mid = ssp(agg @ c1_m2w + b + t) -> B2 (extra==out elementwise-safe)
    node_gemm<2><<<512, 256, gemm_shmem, stream>>>(B1, c1m2w, c1m2b, B2, B2, n);

    // y2 = x_mid @ c2_m1w -> B0
    node_gemm<0><<<512, 256, gemm_shmem, stream>>>(B2, c2m1w, nullptr, nullptr, B0, n);

    // conv2 -> B1
    red_conv<<<2048, 256, 0, stream>>>(B0, wmsg, srcp, off, tnlo, B1, ntiles);

    // x3 = ssp(agg @ c2_m2w + b) -> B0 ; out = ssp(x3 @ lin_w + b) -> d_out
    node_gemm<1><<<512, 256, gemm_shmem, stream>>>(B1, c2m2w, c2m2b, nullptr, B0, n);
    node_gemm<1><<<512, 256, gemm_shmem, stream>>>(B0, linw, linb, nullptr, out, n);
}

// Round 15
// 726.404 us; speedup vs baseline: 1.1512x; 1.1512x over previous
//
#include <hip/hip_runtime.h>
#include <hip/hip_bf16.h>
#include <math.h>

#define NF 128
#define EC 50
#define ET 64              // edges per MFMA tile/pass
#define SCH 2048           // scan chunk size
#define CUTOFF 0.8f
#define PI_F 3.14159265358979323846f

typedef __attribute__((ext_vector_type(8))) _Float16 f16x8;
typedef __attribute__((ext_vector_type(2))) _Float16 f16x2;
typedef __attribute__((ext_vector_type(4))) float f32x4;

__device__ __forceinline__ float4 ld4(const float* p) { return *reinterpret_cast<const float4*>(p); }
__device__ __forceinline__ void st4(float* p, float4 v) { *reinterpret_cast<float4*>(p) = v; }

__device__ __forceinline__ float4 f4fma(float a, float4 w, float4 acc) {
    acc.x = fmaf(a, w.x, acc.x); acc.y = fmaf(a, w.y, acc.y);
    acc.z = fmaf(a, w.z, acc.z); acc.w = fmaf(a, w.w, acc.w);
    return acc;
}

// fast ssp: hardware exp/log; validated R7-R13 (absmax 0.0078)
__device__ __forceinline__ float sspf(float x) {
    return fmaxf(x, 0.0f) + __logf(1.0f + __expf(-fabsf(x))) - 0.69314718055994530942f;
}
__device__ __forceinline__ float4 ssp4(float4 v) {
    v.x = sspf(v.x); v.y = sspf(v.y); v.z = sspf(v.z); v.w = sspf(v.w);
    return v;
}
__device__ __forceinline__ float swishf(float x) {
    return x / (1.0f + __expf(-x));
}

// -------------------------------------------------------------------------
__global__ __launch_bounds__(256) void emb_kernel(const float* __restrict__ tt,
                                                  float* __restrict__ emb, int n) {
    int i = blockIdx.x * blockDim.x + threadIdx.x;
    if (i >= n * 64) return;
    int node = i >> 6, k = i & 63;
    float t = tt[node];
    float coef = __expf((float)k * (-6.9077552789821368f / 63.0f));
    float e = t * coef;
    emb[node * NF + k]      = swishf(__sinf(e));
    emb[node * NF + 64 + k] = swishf(__cosf(e));
}

// -------------------------------------------------------------------------
// out[N,128] = f(A[N,128] @ W[128,128] (+bias) (+extra))  — R7-proven version
template<int MODE>
__global__ __launch_bounds__(256) void node_gemm(const float* A,
                                                 const float* __restrict__ W,
                                                 const float* __restrict__ bias,
                                                 const float* extra,
                                                 float* out, int n) {
    extern __shared__ float sm[];
    float* W_lds = sm;            // 128*128
    float* A_lds = sm + NF * NF;  // 32*128
    const int tid = threadIdx.x;
    const int cg = tid & 31;
    const int rg = tid >> 5;

    for (int idx = tid * 4; idx < NF * NF; idx += 1024)
        st4(W_lds + idx, ld4(W + idx));

    float4 bv = make_float4(0.f, 0.f, 0.f, 0.f);
    if (MODE != 0) bv = ld4(bias + 4 * cg);

    const int ntile = (n + 31) >> 5;
    for (int tile = blockIdx.x; tile < ntile; tile += gridDim.x) {
        const int base = tile << 5;
        __syncthreads();
        for (int idx = tid * 4; idx < 32 * NF; idx += 1024) {
            int r = idx >> 7;
            int row = base + r;
            float4 v = make_float4(0.f, 0.f, 0.f, 0.f);
            if (row < n) v = ld4(A + row * NF + (idx & 127));
            st4(A_lds + idx, v);
        }
        __syncthreads();

        float4 acc[4] = {bv, bv, bv, bv};
        #pragma unroll 8
        for (int k4 = 0; k4 < 32; k4++) {
            float4 w0 = ld4(W_lds + (4 * k4 + 0) * NF + 4 * cg);
            float4 w1 = ld4(W_lds + (4 * k4 + 1) * NF + 4 * cg);
            float4 w2 = ld4(W_lds + (4 * k4 + 2) * NF + 4 * cg);
            float4 w3 = ld4(W_lds + (4 * k4 + 3) * NF + 4 * cg);
            #pragma unroll
            for (int rr = 0; rr < 4; rr++) {
                float4 a = ld4(A_lds + (rg * 4 + rr) * NF + 4 * k4);
                acc[rr] = f4fma(a.x, w0, acc[rr]);
                acc[rr] = f4fma(a.y, w1, acc[rr]);
                acc[rr] = f4fma(a.z, w2, acc[rr]);
                acc[rr] = f4fma(a.w, w3, acc[rr]);
            }
        }
        #pragma unroll
        for (int rr = 0; rr < 4; rr++) {
            int row = base + rg * 4 + rr;
            if (row >= n) continue;
            float4 v = acc[rr];
            if (MODE == 2) {
                float4 e4 = ld4(extra + row * NF + 4 * cg);
                v.x += e4.x; v.y += e4.y; v.z += e4.z; v.w += e4.w;
            }
            if (MODE == 1 || MODE == 2) v = ssp4(v);
            st4(out + row * NF + 4 * cg, v);
        }
    }
}

// -------------------------------------------------------------------------
// CSR build: degree -> 3-phase multi-block exclusive scan -> scatter.
__global__ __launch_bounds__(256) void deg_kernel(const int* __restrict__ ei,
                                                  int* __restrict__ deg, int E_) {
    int e = blockIdx.x * blockDim.x + threadIdx.x;
    if (e < E_) atomicAdd(&deg[ei[E_ + e]], 1);
}

// phase 1: per-chunk sums (one block per SCH-element chunk)
__global__ __launch_bounds__(256) void scan_chunk(const int* __restrict__ deg,
                                                  int* __restrict__ csum, int n) {
    int base = blockIdx.x * SCH;
    int s = 0;
    for (int i = threadIdx.x; i < SCH; i += 256) {
        int idx = base + i;
        if (idx < n) s += deg[idx];
    }
    __shared__ int red[4];
    #pragma unroll
    for (int d = 1; d < 64; d <<= 1) s += __shfl_xor(s, d);
    if ((threadIdx.x & 63) == 0) red[threadIdx.x >> 6] = s;
    __syncthreads();
    if (threadIdx.x == 0) csum[blockIdx.x] = red[0] + red[1] + red[2] + red[3];
}

// phase 2: exclusive scan of chunk sums (nch <= 1024); also off[n] = E (known)
__global__ __launch_bounds__(1024) void scan_csum_k(const int* __restrict__ csum,
                                                    int* __restrict__ coff, int nch,
                                                    int* __restrict__ off, int n, int E_) {
    __shared__ int sm[1024];
    const int tid = threadIdx.x;
    int v = (tid < nch) ? csum[tid] : 0;
    sm[tid] = v;
    __syncthreads();
    for (int st = 1; st < 1024; st <<= 1) {
        int t = (tid >= st) ? sm[tid - st] : 0;
        __syncthreads();
        sm[tid] += t;
        __syncthreads();
    }
    if (tid < nch) coff[tid] = sm[tid] - v;   // exclusive
    if (tid == 0) off[n] = E_;                // total degree == E
}

// phase 3: per-chunk local exclusive scan + chunk offset -> off
__global__ __launch_bounds__(256) void scan_emit(const int* __restrict__ deg,
                                                 const int* __restrict__ coff,
                                                 int* __restrict__ off, int n) {
    const int base = blockIdx.x * SCH + threadIdx.x * 8;
    int vals[8]; int s = 0;
    #pragma unroll
    for (int j = 0; j < 8; j++) {
        int idx = base + j;
        vals[j] = (idx < n) ? deg[idx] : 0;
        s += vals[j];
    }
    __shared__ int ts[256];
    ts[threadIdx.x] = s;
    __syncthreads();
    for (int st = 1; st < 256; st <<= 1) {
        int t = (threadIdx.x >= st) ? ts[threadIdx.x - st] : 0;
        __syncthreads();
        ts[threadIdx.x] += t;
        __syncthreads();
    }
    int prefix = coff[blockIdx.x] + ts[threadIdx.x] - s;
    #pragma unroll
    for (int j = 0; j < 8; j++) {
        int idx = base + j;
        if (idx < n) off[idx] = prefix;
        prefix += vals[j];
    }
}

__global__ __launch_bounds__(256) void scatter_kernel(const int* __restrict__ ei,
                                                      const float* __restrict__ elen,
                                                      const int* __restrict__ off,
                                                      int* __restrict__ cur,
                                                      int* __restrict__ perm,
                                                      int* __restrict__ srcp,
                                                      float* __restrict__ Cp, int E_) {
    int e = blockIdx.x * blockDim.x + threadIdx.x;
    if (e < E_) {
        int d = ei[E_ + e];
        int p = off[d] + atomicAdd(&cur[d], 1);
        perm[p] = e;
        srcp[p] = ei[e];
        float len = elen[e];
        float c = 0.5f * (__cosf(len * (PI_F / CUTOFF)) + 1.0f);
        Cp[p] = (len <= CUTOFF && len >= 0.0f) ? c : 0.0f;
    }
}

// tnlo[t] = first node n with off[n] >= 64*t (tile ownership table)
__global__ __launch_bounds__(256) void tilebnd_kernel(const int* __restrict__ off,
                                                      int* __restrict__ tnlo,
                                                      int nN, int ntiles) {
    int t = blockIdx.x * blockDim.x + threadIdx.x;
    if (t > ntiles) return;
    if (t == ntiles) { tnlo[t] = nN; return; }
    int key = t * ET;
    int lo = 0, hi = nN + 1;
    while (lo < hi) { int mid = (lo + hi) >> 1; if (off[mid] < key) lo = mid + 1; else hi = mid; }
    tnlo[t] = lo;
}

// -------------------------------------------------------------------------
// FAST PATH kernel 1: wf_kernel — dense 64-edge MFMA tiles, writes
// msg = Wf*C (fp16, CSR order) to global. Conv-invariant: run ONCE.
// (256,3) REQUIRED: cap 170 fits the ~116-130 unified VGPR+AGPR need.
// (256,4) cap 128 spilled (R14: VGPR 64, FETCH +233MB, dur 232->330).
__global__ __launch_bounds__(256, 3) void wf_kernel(const float* __restrict__ eattr,
                                                    const float* __restrict__ em1w,
                                                    const float* __restrict__ em1b,
                                                    const float* __restrict__ em2w,
                                                    const float* __restrict__ em2b,
                                                    const int* __restrict__ perm,
                                                    const float* __restrict__ Cp,
                                                    unsigned int* __restrict__ wmsg32,
                                                    int E_) {
    __shared__ __align__(16) char U[ET * 128 + ET * 256];
    __shared__ float C_sm[ET];
    char* ea_p  = U;
    char* h_p   = U + ET * 128;
    char* msg_b = U;               // [64] rows x 264B (132 fp16), overlays ea/h

    const int tid  = threadIdx.x;
    const int wid  = tid >> 6;
    const int lane = tid & 63;
    const int l15  = lane & 15;
    const int lhi  = lane >> 4;

    f16x8 w1f[2][2];
    f16x8 w2f[2][4];
    float b1c[2], b2c[2];
    #pragma unroll
    for (int ct = 0; ct < 2; ct++) {
        const int col = (2 * wid + ct) * 16 + l15;
        b1c[ct] = em1b[col];
        b2c[ct] = em2b[col];
        #pragma unroll
        for (int t = 0; t < 2; t++)
            #pragma unroll
            for (int j = 0; j < 8; j++) {
                int k = t * 32 + lhi * 8 + j;
                w1f[ct][t][j] = (_Float16)((k < EC) ? em1w[k * NF + col] : 0.0f);
            }
        #pragma unroll
        for (int t = 0; t < 4; t++)
            #pragma unroll
            for (int j = 0; j < 8; j++) {
                int k = t * 32 + lhi * 8 + j;
                w2f[ct][t][j] = (_Float16)em2w[k * NF + col];
            }
    }

    const int ntiles = (E_ + ET - 1) / ET;
    for (int tile = blockIdx.x; tile < ntiles; tile += gridDim.x) {
        const int base = tile * ET;
        const int ec = min(ET, E_ - base);
        const int mmax = (ec + 15) >> 4;
        __syncthreads();   // prev copy done

        if (tid < ET) C_sm[tid] = (tid < ec) ? Cp[base + tid] : 0.0f;
        {
            int row = tid >> 2, part = tid & 3;
            bool val = row < ec;
            const float* ep = eattr + (size_t)(val ? perm[base + row] : 0) * EC;
            #pragma unroll
            for (int kk = 0; kk < 16; kk += 2) {
                int k = part * 16 + kk;
                float2 v = make_float2(0.f, 0.f);
                if (val && k <= 48) v = *(const float2*)(ep + k);
                f16x2 pk;
                pk[0] = (_Float16)v.x; pk[1] = (_Float16)v.y;
                *(f16x2*)(ea_p + row * 128 + ((2 * k) ^ ((row & 7) << 4))) = pk;
            }
        }
        __syncthreads();

        // layer 1
        f32x4 acc[4][2];
        #pragma unroll
        for (int m = 0; m < 4; m++) {
            if (m < mmax) {
                #pragma unroll
                for (int ct = 0; ct < 2; ct++) {
                    f32x4 b = {b1c[ct], b1c[ct], b1c[ct], b1c[ct]};
                    acc[m][ct] = b;
                }
                const int row = m * 16 + l15;
                #pragma unroll
                for (int t1 = 0; t1 < 2; t1++) {
                    int o = row * 128 + ((t1 * 64 + lhi * 16) ^ ((row & 7) << 4));
                    f16x8 a = *(const f16x8*)(ea_p + o);
                    #pragma unroll
                    for (int ct = 0; ct < 2; ct++)
                        acc[m][ct] = __builtin_amdgcn_mfma_f32_16x16x32_f16(a, w1f[ct][t1], acc[m][ct], 0, 0, 0);
                }
            }
        }
        #pragma unroll
        for (int m = 0; m < 4; m++) {
            if (m < mmax) {
                #pragma unroll
                for (int ct = 0; ct < 2; ct++) {
                    const int col = (2 * wid + ct) * 16 + l15;
                    #pragma unroll
                    for (int r = 0; r < 4; r++) {
                        int row = m * 16 + lhi * 4 + r;
                        *(_Float16*)(h_p + row * 256 + ((2 * col) ^ ((row & 7) << 4))) =
                            (_Float16)sspf(acc[m][ct][r]);
                    }
                }
            }
        }
        __syncthreads();

        // layer 2
        #pragma unroll
        for (int m = 0; m < 4; m++) {
            if (m < mmax) {
                #pragma unroll
                for (int ct = 0; ct < 2; ct++) {
                    f32x4 b = {b2c[ct], b2c[ct], b2c[ct], b2c[ct]};
                    acc[m][ct] = b;
                }
                const int row = m * 16 + l15;
                #pragma unroll
                for (int t2 = 0; t2 < 4; t2++) {
                    int o = row * 256 + ((t2 * 64 + lhi * 16) ^ ((row & 7) << 4));
                    f16x8 a = *(const f16x8*)(h_p + o);
                    #pragma unroll
                    for (int ct = 0; ct < 2; ct++)
                        acc[m][ct] = __builtin_amdgcn_mfma_f32_16x16x32_f16(a, w2f[ct][t2], acc[m][ct], 0, 0, 0);
                }
            }
        }
        __syncthreads();   // h reads done; msg overlays ea/h

        #pragma unroll
        for (int m = 0; m < 4; m++) {
            if (m < mmax) {
                #pragma unroll
                for (int ct = 0; ct < 2; ct++) {
                    #pragma unroll
                    for (int r = 0; r < 4; r++) {
                        int e = m * 16 + lhi * 4 + r;
                        int ch = (2 * wid + ct) * 16 + l15;
                        *(_Float16*)(msg_b + e * 264 + 2 * ch) =
                            (_Float16)(acc[m][ct][r] * C_sm[e]);
                    }
                }
            }
        }
        __syncthreads();

        // coalesced LDS -> global copy (non-temporal: stream, written once)
        for (int j = tid; j < ec * 64; j += 256)
            __builtin_nontemporal_store(
                *(const unsigned int*)(msg_b + (j >> 6) * 264 + (j & 63) * 4),
                &wmsg32[(size_t)base * 64 + j]);
    }
}

// -------------------------------------------------------------------------
// FAST PATH kernel 2: red_conv — pure gather-reduce, no LDS, no barriers.
// 4-deep load batching; wmsg read non-temporally (each row read once per
// conv — keep the 205MB stream from evicting reused y rows in L2).
__global__ __launch_bounds__(256) void red_conv(const float* __restrict__ y,
                                                const unsigned int* __restrict__ wmsg32,
                                                const int* __restrict__ srcp,
                                                const int* __restrict__ off,
                                                const int* __restrict__ tnlo,
                                                float* __restrict__ agg,
                                                int ntiles) {
    const int wid  = threadIdx.x >> 6;
    const int lane = threadIdx.x & 63;
    const int c2   = lane * 2;

    for (int tile = blockIdx.x; tile < ntiles; tile += gridDim.x) {
        const int n_lo = tnlo[tile], n_hi1 = tnlo[tile + 1];
        for (int n = n_lo + wid; n < n_hi1; n += 4) {
            float2 a = make_float2(0.f, 0.f);
            int i = off[n];
            const int e1 = off[n + 1];
            for (; i + 4 <= e1; i += 4) {
                int s0 = srcp[i], s1 = srcp[i + 1], s2 = srcp[i + 2], s3 = srcp[i + 3];
                unsigned int u0 = __builtin_nontemporal_load(&wmsg32[(size_t)(i    ) * 64 + lane]);
                unsigned int u1 = __builtin_nontemporal_load(&wmsg32[(size_t)(i + 1) * 64 + lane]);
                unsigned int u2 = __builtin_nontemporal_load(&wmsg32[(size_t)(i + 2) * 64 + lane]);
                unsigned int u3 = __builtin_nontemporal_load(&wmsg32[(size_t)(i + 3) * 64 + lane]);
                float2 y0 = *(const float2*)(y + (size_t)s0 * NF + c2);
                float2 y1 = *(const float2*)(y + (size_t)s1 * NF + c2);
                float2 y2 = *(const float2*)(y + (size_t)s2 * NF + c2);
                float2 y3 = *(const float2*)(y + (size_t)s3 * NF + c2);
                f16x2 m0 = *(const f16x2*)&u0, m1 = *(const f16x2*)&u1;
                f16x2 m2 = *(const f16x2*)&u2, m3 = *(const f16x2*)&u3;
                a.x = fmaf((float)m0[0], y0.x, a.x); a.y = fmaf((float)m0[1], y0.y, a.y);
                a.x = fmaf((float)m1[0], y1.x, a.x); a.y = fmaf((float)m1[1], y1.y, a.y);
                a.x = fmaf((float)m2[0], y2.x, a.x); a.y = fmaf((float)m2[1], y2.y, a.y);
                a.x = fmaf((float)m3[0], y3.x, a.x); a.y = fmaf((float)m3[1], y3.y, a.y);
            }
            for (; i < e1; i++) {
                unsigned int u = __builtin_nontemporal_load(&wmsg32[(size_t)i * 64 + lane]);
                f16x2 mp = *(const f16x2*)&u;
                float2 yv = *(const float2*)(y + (size_t)srcp[i] * NF + c2);
                a.x = fmaf((float)mp[0], yv.x, a.x);
                a.y = fmaf((float)mp[1], yv.y, a.y);
            }
            *(float2*)(agg + (size_t)n * NF + c2) = a;
        }
    }
}

// -------------------------------------------------------------------------
extern "C" void kernel_launch(void* const* d_in, const int* in_sizes, int n_in,
                              void* d_out, int out_size, void* d_ws, size_t ws_size,
                              hipStream_t stream) {
    const float* tt    = (const float*)d_in[0];
    const float* xx    = (const float*)d_in[1];
    const int*   ei    = (const int*)d_in[2];
    const float* elen  = (const float*)d_in[3];
    const float* eattr = (const float*)d_in[4];
    const float* em1w  = (const float*)d_in[5];
    const float* em1b  = (const float*)d_in[6];
    const float* em2w  = (const float*)d_in[7];
    const float* em2b  = (const float*)d_in[8];
    const float* c1m1w = (const float*)d_in[9];
    const float* c1m2w = (const float*)d_in[10];
    const float* c1m2b = (const float*)d_in[11];
    const float* c2m1w = (const float*)d_in[12];
    const float* c2m2w = (const float*)d_in[13];
    const float* c2m2b = (const float*)d_in[14];
    const float* tew   = (const float*)d_in[15];
    const float* teb   = (const float*)d_in[16];
    const float* linw  = (const float*)d_in[17];
    const float* linb  = (const float*)d_in[18];

    const int n  = in_sizes[0];
    const int E_ = in_sizes[2] / 2;
    const int ntiles = (E_ + ET - 1) / ET;
    const int nch = (n + SCH - 1) / SCH;      // scan chunks (25 @ n=50k)
    float* out = (float*)d_out;

    const size_t NB = (size_t)n * NF;
    float* B0 = (float*)d_ws;   // y1 / y2 / x3
    float* B1 = B0 + NB;        // agg
    float* B2 = B1 + NB;        // emb -> t (in-place) -> x_mid
    int* off  = (int*)(B2 + NB);      // n+1
    int* perm = off + (n + 1);        // E
    int* deg  = perm + E_;            // n
    int* cur  = deg + n;              // n (deg+cur contiguous for memset)
    int* srcp = cur + n;              // E
    int* tnlo = srcp + E_;            // ntiles+1
    int* csum = tnlo + ntiles + 1;    // nch
    int* coff = csum + nch;           // nch
    float* Cp = (float*)(coff + nch); // E
    unsigned int* wmsg32 = (unsigned int*)(Cp + E_);   // E*64 u32 (=E*128 fp16)

    const size_t gemm_shmem = (size_t)(NF * NF + 32 * NF) * sizeof(float);   // 80 KB

    // ---- CSR build (multi-block scan) + ownership table
    hipMemsetAsync(deg, 0, (size_t)2 * n * sizeof(int), stream);
    deg_kernel<<<(E_ + 255) / 256, 256, 0, stream>>>(ei, deg, E_);
    scan_chunk<<<nch, 256, 0, stream>>>(deg, csum, n);
    scan_csum_k<<<1, 1024, 0, stream>>>(csum, coff, nch, off, n, E_);
    scan_emit<<<nch, 256, 0, stream>>>(deg, coff, off, n);
    scatter_kernel<<<(E_ + 255) / 256, 256, 0, stream>>>(ei, elen, off, cur,
                                                         perm, srcp, Cp, E_);
    tilebnd_kernel<<<(ntiles + 256) / 256, 256, 0, stream>>>(off, tnlo, n, ntiles);

    // emb -> B2 ; t = swish_emb @ te_w + te_b -> B2 (in-place safe)
    emb_kernel<<<(n * 64 + 255) / 256, 256, 0, stream>>>(tt, B2, n);
    node_gemm<3><<<512, 256, gemm_shmem, stream>>>(B2, tew, teb, nullptr, B2, n);

    // msg = Wf*C (conv-invariant) computed ONCE
    wf_kernel<<<2048, 256, 0, stream>>>(eattr, em1w, em1b, em2w, em2b,
                                        perm, Cp, wmsg32, E_);

    // y1 = xx @ c1_m1w -> B0
    node_gemm<0><<<512, 256, gemm_shmem, stream>>>(xx, c1m1w, nullptr, nullptr, B0, n);

    // conv1 -> B1
    red_conv<<<2048, 256, 0, stream>>>(B0, wmsg32, srcp, off, tnlo, B1, ntiles);

    // x_mid = ssp(agg @ c1_m2w + b + t) -> B2 (extra==out elementwise-safe)
    node_gemm<2><<<512, 256, gemm_shmem, stream>>>(B1, c1m2w, c1m2b, B2, B2, n);

    // y2 = x_mid @ c2_m1w -> B0
    node_gemm<0><<<512, 256, gemm_shmem, stream>>>(B2, c2m1w, nullptr, nullptr, B0, n);

    // conv2 -> B1
    red_conv<<<2048, 256, 0, stream>>>(B0, wmsg32, srcp, off, tnlo, B1, ntiles);

    // x3 = ssp(agg @ c2_m2w + b) -> B0 ; out = ssp(x3 @ lin_w + b) -> d_out
    node_gemm<1><<<512, 256, gemm_shmem, stream>>>(B1, c2m2w, c2m2b, nullptr, B0, n);
    node_gemm<1><<<512, 256, gemm_shmem, stream>>>(B0, linw, linb, nullptr, out, n);
}

// Round 16
// 636.018 us; speedup vs baseline: 1.3147x; 1.1421x over previous
//
#include <hip/hip_runtime.h>
#include <hip/hip_bf16.h>
#include <math.h>

#define NF 128
#define EC 50
#define ET 64              // edges per MFMA tile/pass
#define SCH 2048           // scan chunk size
#define CUTOFF 0.8f
#define PI_F 3.14159265358979323846f

typedef __attribute__((ext_vector_type(8))) _Float16 f16x8;
typedef __attribute__((ext_vector_type(2))) _Float16 f16x2;
typedef __attribute__((ext_vector_type(4))) float f32x4;

__device__ __forceinline__ float4 ld4(const float* p) { return *reinterpret_cast<const float4*>(p); }

// fast ssp: hardware exp/log; validated R7-R15 (absmax 0.0078)
__device__ __forceinline__ float sspf(float x) {
    return fmaxf(x, 0.0f) + __logf(1.0f + __expf(-fabsf(x))) - 0.69314718055994530942f;
}
__device__ __forceinline__ float swishf(float x) {
    return x / (1.0f + __expf(-x));
}

// -------------------------------------------------------------------------
__global__ __launch_bounds__(256) void emb_kernel(const float* __restrict__ tt,
                                                  float* __restrict__ emb, int n) {
    int i = blockIdx.x * blockDim.x + threadIdx.x;
    if (i >= n * 64) return;
    int node = i >> 6, k = i & 63;
    float t = tt[node];
    float coef = __expf((float)k * (-6.9077552789821368f / 63.0f));
    float e = t * coef;
    emb[node * NF + k]      = swishf(__sinf(e));
    emb[node * NF + 64 + k] = swishf(__cosf(e));
}

// -------------------------------------------------------------------------
// MFMA node GEMM: out[N,128] = f(A[N,128] @ W[128,128] (+bias) (+extra)).
// A staged to LDS fp16 in the wf-verified swizzled layout (row*256 +
// ((2k)^((row&7)<<4))); W in VGPRs as the wf w2f fragment; f32 accumulate.
// MODE 0: plain. MODE 1: ssp(.+b). MODE 2: ssp(.+b+extra). MODE 3: .+b
// In-place safe: whole tile staged to LDS + barrier before any store;
// extra==out read-before-write per thread.
template<int MODE>
__global__ void mfma_gemm(const float* A,
                          const float* __restrict__ W,
                          const float* __restrict__ bias,
                          const float* extra,
                          float* out, int n) {
    __shared__ __align__(16) char A_lds[64 * 256];   // [64 rows][128 k] fp16 swizzled
    const int tid  = threadIdx.x;
    const int wid  = tid >> 6;
    const int lane = tid & 63;
    const int l15  = lane & 15;
    const int lhi  = lane >> 4;

    // preload W B-fragments (wf w2f layout): lane holds W[k=t*32+lhi*8+j][col]
    f16x8 wfr[2][4];
    float bc[2];
    #pragma unroll
    for (int ct = 0; ct < 2; ct++) {
        const int col = (2 * wid + ct) * 16 + l15;
        bc[ct] = (MODE != 0) ? bias[col] : 0.0f;
        #pragma unroll
        for (int t = 0; t < 4; t++)
            #pragma unroll
            for (int j = 0; j < 8; j++) {
                int k = t * 32 + lhi * 8 + j;
                wfr[ct][t][j] = (_Float16)W[k * NF + col];
            }
    }

    const int ntile = (n + 63) >> 6;
    for (int tile = blockIdx.x; tile < ntile; tile += gridDim.x) {
        const int base = tile << 6;
        __syncthreads();
        // stage A tile -> fp16 swizzled LDS (row = tid>>2, 32 k's per thread)
        {
            int row = tid >> 2, part = tid & 3;
            int grow = base + row;
            bool val = grow < n;
            const float* ap = A + (size_t)grow * NF + part * 32;
            #pragma unroll
            for (int kk = 0; kk < 32; kk += 4) {
                float4 v = val ? ld4(ap + kk) : make_float4(0.f, 0.f, 0.f, 0.f);
                int k = part * 32 + kk;
                f16x2 p0; p0[0] = (_Float16)v.x; p0[1] = (_Float16)v.y;
                f16x2 p1; p1[0] = (_Float16)v.z; p1[1] = (_Float16)v.w;
                *(f16x2*)(A_lds + row * 256 + ((2 * k)       ^ ((row & 7) << 4))) = p0;
                *(f16x2*)(A_lds + row * 256 + ((2 * (k + 2)) ^ ((row & 7) << 4))) = p1;
            }
        }
        __syncthreads();

        f32x4 acc[4][2];
        #pragma unroll
        for (int m = 0; m < 4; m++) {
            #pragma unroll
            for (int ct = 0; ct < 2; ct++) {
                f32x4 b = {bc[ct], bc[ct], bc[ct], bc[ct]};
                acc[m][ct] = b;
            }
            const int row = m * 16 + l15;
            #pragma unroll
            for (int t2 = 0; t2 < 4; t2++) {
                int o = row * 256 + ((t2 * 64 + lhi * 16) ^ ((row & 7) << 4));
                f16x8 a = *(const f16x8*)(A_lds + o);
                #pragma unroll
                for (int ct = 0; ct < 2; ct++)
                    acc[m][ct] = __builtin_amdgcn_mfma_f32_16x16x32_f16(a, wfr[ct][t2], acc[m][ct], 0, 0, 0);
            }
        }

        // epilogue: D row = m*16+lhi*4+r, col = (2wid+ct)*16+l15
        #pragma unroll
        for (int m = 0; m < 4; m++) {
            #pragma unroll
            for (int ct = 0; ct < 2; ct++) {
                const int col = (2 * wid + ct) * 16 + l15;
                #pragma unroll
                for (int r = 0; r < 4; r++) {
                    int grow = base + m * 16 + lhi * 4 + r;
                    if (grow >= n) continue;
                    float v = acc[m][ct][r];
                    if (MODE == 2) v += extra[(size_t)grow * NF + col];
                    if (MODE == 1 || MODE == 2) v = sspf(v);
                    out[(size_t)grow * NF + col] = v;
                }
            }
        }
    }
}

// -------------------------------------------------------------------------
// CSR build: degree -> 3-phase multi-block exclusive scan -> scatter.
__global__ __launch_bounds__(256) void deg_kernel(const int* __restrict__ ei,
                                                  int* __restrict__ deg, int E_) {
    int e = blockIdx.x * blockDim.x + threadIdx.x;
    if (e < E_) atomicAdd(&deg[ei[E_ + e]], 1);
}

__global__ __launch_bounds__(256) void scan_chunk(const int* __restrict__ deg,
                                                  int* __restrict__ csum, int n) {
    int base = blockIdx.x * SCH;
    int s = 0;
    for (int i = threadIdx.x; i < SCH; i += 256) {
        int idx = base + i;
        if (idx < n) s += deg[idx];
    }
    __shared__ int red[4];
    #pragma unroll
    for (int d = 1; d < 64; d <<= 1) s += __shfl_xor(s, d);
    if ((threadIdx.x & 63) == 0) red[threadIdx.x >> 6] = s;
    __syncthreads();
    if (threadIdx.x == 0) csum[blockIdx.x] = red[0] + red[1] + red[2] + red[3];
}

__global__ __launch_bounds__(1024) void scan_csum_k(const int* __restrict__ csum,
                                                    int* __restrict__ coff, int nch,
                                                    int* __restrict__ off, int n, int E_) {
    __shared__ int sm[1024];
    const int tid = threadIdx.x;
    int v = (tid < nch) ? csum[tid] : 0;
    sm[tid] = v;
    __syncthreads();
    for (int st = 1; st < 1024; st <<= 1) {
        int t = (tid >= st) ? sm[tid - st] : 0;
        __syncthreads();
        sm[tid] += t;
        __syncthreads();
    }
    if (tid < nch) coff[tid] = sm[tid] - v;   // exclusive
    if (tid == 0) off[n] = E_;                // total degree == E
}

__global__ __launch_bounds__(256) void scan_emit(const int* __restrict__ deg,
                                                 const int* __restrict__ coff,
                                                 int* __restrict__ off, int n) {
    const int base = blockIdx.x * SCH + threadIdx.x * 8;
    int vals[8]; int s = 0;
    #pragma unroll
    for (int j = 0; j < 8; j++) {
        int idx = base + j;
        vals[j] = (idx < n) ? deg[idx] : 0;
        s += vals[j];
    }
    __shared__ int ts[256];
    ts[threadIdx.x] = s;
    __syncthreads();
    for (int st = 1; st < 256; st <<= 1) {
        int t = (threadIdx.x >= st) ? ts[threadIdx.x - st] : 0;
        __syncthreads();
        ts[threadIdx.x] += t;
        __syncthreads();
    }
    int prefix = coff[blockIdx.x] + ts[threadIdx.x] - s;
    #pragma unroll
    for (int j = 0; j < 8; j++) {
        int idx = base + j;
        if (idx < n) off[idx] = prefix;
        prefix += vals[j];
    }
}

__global__ __launch_bounds__(256) void scatter_kernel(const int* __restrict__ ei,
                                                      const float* __restrict__ elen,
                                                      const int* __restrict__ off,
                                                      int* __restrict__ cur,
                                                      int* __restrict__ perm,
                                                      int* __restrict__ srcp,
                                                      float* __restrict__ Cp, int E_) {
    int e = blockIdx.x * blockDim.x + threadIdx.x;
    if (e < E_) {
        int d = ei[E_ + e];
        int p = off[d] + atomicAdd(&cur[d], 1);
        perm[p] = e;
        srcp[p] = ei[e];
        float len = elen[e];
        float c = 0.5f * (__cosf(len * (PI_F / CUTOFF)) + 1.0f);
        Cp[p] = (len <= CUTOFF && len >= 0.0f) ? c : 0.0f;
    }
}

// tnlo[t] = first node n with off[n] >= 64*t (tile ownership table)
__global__ __launch_bounds__(256) void tilebnd_kernel(const int* __restrict__ off,
                                                      int* __restrict__ tnlo,
                                                      int nN, int ntiles) {
    int t = blockIdx.x * blockDim.x + threadIdx.x;
    if (t > ntiles) return;
    if (t == ntiles) { tnlo[t] = nN; return; }
    int key = t * ET;
    int lo = 0, hi = nN + 1;
    while (lo < hi) { int mid = (lo + hi) >> 1; if (off[mid] < key) lo = mid + 1; else hi = mid; }
    tnlo[t] = lo;
}

// -------------------------------------------------------------------------
// wf_kernel — dense 64-edge MFMA tiles, writes msg = Wf*C (fp16, CSR order).
// Conv-invariant: run ONCE. (256,3) REQUIRED (R14: (256,4) cap 128 spilled).
__global__ __launch_bounds__(256, 3) void wf_kernel(const float* __restrict__ eattr,
                                                    const float* __restrict__ em1w,
                                                    const float* __restrict__ em1b,
                                                    const float* __restrict__ em2w,
                                                    const float* __restrict__ em2b,
                                                    const int* __restrict__ perm,
                                                    const float* __restrict__ Cp,
                                                    unsigned int* __restrict__ wmsg32,
                                                    int E_) {
    __shared__ __align__(16) char U[ET * 128 + ET * 256];
    __shared__ float C_sm[ET];
    char* ea_p  = U;
    char* h_p   = U + ET * 128;
    char* msg_b = U;               // [64] rows x 264B (132 fp16), overlays ea/h

    const int tid  = threadIdx.x;
    const int wid  = tid >> 6;
    const int lane = tid & 63;
    const int l15  = lane & 15;
    const int lhi  = lane >> 4;

    f16x8 w1f[2][2];
    f16x8 w2f[2][4];
    float b1c[2], b2c[2];
    #pragma unroll
    for (int ct = 0; ct < 2; ct++) {
        const int col = (2 * wid + ct) * 16 + l15;
        b1c[ct] = em1b[col];
        b2c[ct] = em2b[col];
        #pragma unroll
        for (int t = 0; t < 2; t++)
            #pragma unroll
            for (int j = 0; j < 8; j++) {
                int k = t * 32 + lhi * 8 + j;
                w1f[ct][t][j] = (_Float16)((k < EC) ? em1w[k * NF + col] : 0.0f);
            }
        #pragma unroll
        for (int t = 0; t < 4; t++)
            #pragma unroll
            for (int j = 0; j < 8; j++) {
                int k = t * 32 + lhi * 8 + j;
                w2f[ct][t][j] = (_Float16)em2w[k * NF + col];
            }
    }

    const int ntiles = (E_ + ET - 1) / ET;
    for (int tile = blockIdx.x; tile < ntiles; tile += gridDim.x) {
        const int base = tile * ET;
        const int ec = min(ET, E_ - base);
        const int mmax = (ec + 15) >> 4;
        __syncthreads();   // prev copy done

        if (tid < ET) C_sm[tid] = (tid < ec) ? Cp[base + tid] : 0.0f;
        {
            int row = tid >> 2, part = tid & 3;
            bool val = row < ec;
            const float* ep = eattr + (size_t)(val ? perm[base + row] : 0) * EC;
            #pragma unroll
            for (int kk = 0; kk < 16; kk += 2) {
                int k = part * 16 + kk;
                float2 v = make_float2(0.f, 0.f);
                if (val && k <= 48) v = *(const float2*)(ep + k);
                f16x2 pk;
                pk[0] = (_Float16)v.x; pk[1] = (_Float16)v.y;
                *(f16x2*)(ea_p + row * 128 + ((2 * k) ^ ((row & 7) << 4))) = pk;
            }
        }
        __syncthreads();

        // layer 1
        f32x4 acc[4][2];
        #pragma unroll
        for (int m = 0; m < 4; m++) {
            if (m < mmax) {
                #pragma unroll
                for (int ct = 0; ct < 2; ct++) {
                    f32x4 b = {b1c[ct], b1c[ct], b1c[ct], b1c[ct]};
                    acc[m][ct] = b;
                }
                const int row = m * 16 + l15;
                #pragma unroll
                for (int t1 = 0; t1 < 2; t1++) {
                    int o = row * 128 + ((t1 * 64 + lhi * 16) ^ ((row & 7) << 4));
                    f16x8 a = *(const f16x8*)(ea_p + o);
                    #pragma unroll
                    for (int ct = 0; ct < 2; ct++)
                        acc[m][ct] = __builtin_amdgcn_mfma_f32_16x16x32_f16(a, w1f[ct][t1], acc[m][ct], 0, 0, 0);
                }
            }
        }
        #pragma unroll
        for (int m = 0; m < 4; m++) {
            if (m < mmax) {
                #pragma unroll
                for (int ct = 0; ct < 2; ct++) {
                    const int col = (2 * wid + ct) * 16 + l15;
                    #pragma unroll
                    for (int r = 0; r < 4; r++) {
                        int row = m * 16 + lhi * 4 + r;
                        *(_Float16*)(h_p + row * 256 + ((2 * col) ^ ((row & 7) << 4))) =
                            (_Float16)sspf(acc[m][ct][r]);
                    }
                }
            }
        }
        __syncthreads();

        // layer 2
        #pragma unroll
        for (int m = 0; m < 4; m++) {
            if (m < mmax) {
                #pragma unroll
                for (int ct = 0; ct < 2; ct++) {
                    f32x4 b = {b2c[ct], b2c[ct], b2c[ct], b2c[ct]};
                    acc[m][ct] = b;
                }
                const int row = m * 16 + l15;
                #pragma unroll
                for (int t2 = 0; t2 < 4; t2++) {
                    int o = row * 256 + ((t2 * 64 + lhi * 16) ^ ((row & 7) << 4));
                    f16x8 a = *(const f16x8*)(h_p + o);
                    #pragma unroll
                    for (int ct = 0; ct < 2; ct++)
                        acc[m][ct] = __builtin_amdgcn_mfma_f32_16x16x32_f16(a, w2f[ct][t2], acc[m][ct], 0, 0, 0);
                }
            }
        }
        __syncthreads();   // h reads done; msg overlays ea/h

        #pragma unroll
        for (int m = 0; m < 4; m++) {
            if (m < mmax) {
                #pragma unroll
                for (int ct = 0; ct < 2; ct++) {
                    #pragma unroll
                    for (int r = 0; r < 4; r++) {
                        int e = m * 16 + lhi * 4 + r;
                        int ch = (2 * wid + ct) * 16 + l15;
                        *(_Float16*)(msg_b + e * 264 + 2 * ch) =
                            (_Float16)(acc[m][ct][r] * C_sm[e]);
                    }
                }
            }
        }
        __syncthreads();

        // coalesced LDS -> global copy (non-temporal stream)
        for (int j = tid; j < ec * 64; j += 256)
            __builtin_nontemporal_store(
                *(const unsigned int*)(msg_b + (j >> 6) * 264 + (j & 63) * 4),
                &wmsg32[(size_t)base * 64 + j]);
    }
}

// -------------------------------------------------------------------------
// red_conv — pure gather-reduce, no LDS, no barriers. 4-deep load batching;
// wmsg read non-temporally (read once per conv; protect y reuse in L2).
__global__ __launch_bounds__(256) void red_conv(const float* __restrict__ y,
                                                const unsigned int* __restrict__ wmsg32,
                                                const int* __restrict__ srcp,
                                                const int* __restrict__ off,
                                                const int* __restrict__ tnlo,
                                                float* __restrict__ agg,
                                                int ntiles) {
    const int wid  = threadIdx.x >> 6;
    const int lane = threadIdx.x & 63;
    const int c2   = lane * 2;

    for (int tile = blockIdx.x; tile < ntiles; tile += gridDim.x) {
        const int n_lo = tnlo[tile], n_hi1 = tnlo[tile + 1];
        for (int n = n_lo + wid; n < n_hi1; n += 4) {
            float2 a = make_float2(0.f, 0.f);
            int i = off[n];
            const int e1 = off[n + 1];
            for (; i + 4 <= e1; i += 4) {
                int s0 = srcp[i], s1 = srcp[i + 1], s2 = srcp[i + 2], s3 = srcp[i + 3];
                unsigned int u0 = __builtin_nontemporal_load(&wmsg32[(size_t)(i    ) * 64 + lane]);
                unsigned int u1 = __builtin_nontemporal_load(&wmsg32[(size_t)(i + 1) * 64 + lane]);
                unsigned int u2 = __builtin_nontemporal_load(&wmsg32[(size_t)(i + 2) * 64 + lane]);
                unsigned int u3 = __builtin_nontemporal_load(&wmsg32[(size_t)(i + 3) * 64 + lane]);
                float2 y0 = *(const float2*)(y + (size_t)s0 * NF + c2);
                float2 y1 = *(const float2*)(y + (size_t)s1 * NF + c2);
                float2 y2 = *(const float2*)(y + (size_t)s2 * NF + c2);
                float2 y3 = *(const float2*)(y + (size_t)s3 * NF + c2);
                f16x2 m0 = *(const f16x2*)&u0, m1 = *(const f16x2*)&u1;
                f16x2 m2 = *(const f16x2*)&u2, m3 = *(const f16x2*)&u3;
                a.x = fmaf((float)m0[0], y0.x, a.x); a.y = fmaf((float)m0[1], y0.y, a.y);
                a.x = fmaf((float)m1[0], y1.x, a.x); a.y = fmaf((float)m1[1], y1.y, a.y);
                a.x = fmaf((float)m2[0], y2.x, a.x); a.y = fmaf((float)m2[1], y2.y, a.y);
                a.x = fmaf((float)m3[0], y3.x, a.x); a.y = fmaf((float)m3[1], y3.y, a.y);
            }
            for (; i < e1; i++) {
                unsigned int u = __builtin_nontemporal_load(&wmsg32[(size_t)i * 64 + lane]);
                f16x2 mp = *(const f16x2*)&u;
                float2 yv = *(const float2*)(y + (size_t)srcp[i] * NF + c2);
                a.x = fmaf((float)mp[0], yv.x, a.x);
                a.y = fmaf((float)mp[1], yv.y, a.y);
            }
            *(float2*)(agg + (size_t)n * NF + c2) = a;
        }
    }
}

// -------------------------------------------------------------------------
extern "C" void kernel_launch(void* const* d_in, const int* in_sizes, int n_in,
                              void* d_out, int out_size, void* d_ws, size_t ws_size,
                              hipStream_t stream) {
    const float* tt    = (const float*)d_in[0];
    const float* xx    = (const float*)d_in[1];
    const int*   ei    = (const int*)d_in[2];
    const float* elen  = (const float*)d_in[3];
    const float* eattr = (const float*)d_in[4];
    const float* em1w  = (const float*)d_in[5];
    const float* em1b  = (const float*)d_in[6];
    const float* em2w  = (const float*)d_in[7];
    const float* em2b  = (const float*)d_in[8];
    const float* c1m1w = (const float*)d_in[9];
    const float* c1m2w = (const float*)d_in[10];
    const float* c1m2b = (const float*)d_in[11];
    const float* c2m1w = (const float*)d_in[12];
    const float* c2m2w = (const float*)d_in[13];
    const float* c2m2b = (const float*)d_in[14];
    const float* tew   = (const float*)d_in[15];
    const float* teb   = (const float*)d_in[16];
    const float* linw  = (const float*)d_in[17];
    const float* linb  = (const float*)d_in[18];

    const int n  = in_sizes[0];
    const int E_ = in_sizes[2] / 2;
    const int ntiles = (E_ + ET - 1) / ET;
    const int gtiles = (n + 63) >> 6;         // mfma_gemm tiles (782 @ n=50k)
    const int nch = (n + SCH - 1) / SCH;      // scan chunks (25 @ n=50k)
    float* out = (float*)d_out;

    const size_t NB = (size_t)n * NF;
    float* B0 = (float*)d_ws;   // y1 / y2 / x3
    float* B1 = B0 + NB;        // agg
    float* B2 = B1 + NB;        // emb -> t (in-place) -> x_mid
    int* off  = (int*)(B2 + NB);      // n+1
    int* perm = off + (n + 1);        // E
    int* deg  = perm + E_;            // n
    int* cur  = deg + n;              // n (deg+cur contiguous for memset)
    int* srcp = cur + n;              // E
    int* tnlo = srcp + E_;            // ntiles+1
    int* csum = tnlo + ntiles + 1;    // nch
    int* coff = csum + nch;           // nch
    float* Cp = (float*)(coff + nch); // E
    unsigned int* wmsg32 = (unsigned int*)(Cp + E_);   // E*64 u32 (=E*128 fp16)

    // ---- CSR build (multi-block scan) + ownership table
    hipMemsetAsync(deg, 0, (size_t)2 * n * sizeof(int), stream);
    deg_kernel<<<(E_ + 255) / 256, 256, 0, stream>>>(ei, deg, E_);
    scan_chunk<<<nch, 256, 0, stream>>>(deg, csum, n);
    scan_csum_k<<<1, 1024, 0, stream>>>(csum, coff, nch, off, n, E_);
    scan_emit<<<nch, 256, 0, stream>>>(deg, coff, off, n);
    scatter_kernel<<<(E_ + 255) / 256, 256, 0, stream>>>(ei, elen, off, cur,
                                                         perm, srcp, Cp, E_);
    tilebnd_kernel<<<(ntiles + 256) / 256, 256, 0, stream>>>(off, tnlo, n, ntiles);

    // emb -> B2 ; t = swish_emb @ te_w + te_b -> B2 (in-place safe)
    emb_kernel<<<(n * 64 + 255) / 256, 256, 0, stream>>>(tt, B2, n);
    mfma_gemm<3><<<gtiles, 256, 0, stream>>>(B2, tew, teb, nullptr, B2, n);

    // msg = Wf*C (conv-invariant) computed ONCE
    wf_kernel<<<2048, 256, 0, stream>>>(eattr, em1w, em1b, em2w, em2b,
                                        perm, Cp, wmsg32, E_);

    // y1 = xx @ c1_m1w -> B0
    mfma_gemm<0><<<gtiles, 256, 0, stream>>>(xx, c1m1w, nullptr, nullptr, B0, n);

    // conv1 -> B1
    red_conv<<<4096, 256, 0, stream>>>(B0, wmsg32, srcp, off, tnlo, B1, ntiles);

    // x_mid = ssp(agg @ c1_m2w + b + t) -> B2 (extra==out elementwise-safe)
    mfma_gemm<2><<<gtiles, 256, 0, stream>>>(B1, c1m2w, c1m2b, B2, B2, n);

    // y2 = x_mid @ c2_m1w -> B0
    mfma_gemm<0><<<gtiles, 256, 0, stream>>>(B2, c2m1w, nullptr, nullptr, B0, n);

    // conv2 -> B1
    red_conv<<<4096, 256, 0, stream>>>(B0, wmsg32, srcp, off, tnlo, B1, ntiles);

    // x3 = ssp(agg @ c2_m2w + b) -> B0 ; out = ssp(x3 @ lin_w + b) -> d_out
    mfma_gemm<1><<<gtiles, 256, 0, stream>>>(B1, c2m2w, c2m2b, nullptr, B0, n);
    mfma_gemm<1><<<gtiles, 256, 0, stream>>>(B0, linw, linb, nullptr, out, n);
}

// Round 17
// 635.800 us; speedup vs baseline: 1.3152x; 1.0003x over previous
//
#include <hip/hip_runtime.h>
#include <hip/hip_bf16.h>
#include <math.h>

#define NF 128
#define EC 50
#define ET 64              // edges per MFMA tile/pass
#define SCH 2048           // scan chunk size
#define CUTOFF 0.8f
#define PI_F 3.14159265358979323846f

typedef __attribute__((ext_vector_type(8))) _Float16 f16x8;
typedef __attribute__((ext_vector_type(2))) _Float16 f16x2;
typedef __attribute__((ext_vector_type(4))) float f32x4;

__device__ __forceinline__ float4 ld4(const float* p) { return *reinterpret_cast<const float4*>(p); }

// fast ssp: hardware exp/log; validated R7-R16 (absmax <= 0.0078)
__device__ __forceinline__ float sspf(float x) {
    return fmaxf(x, 0.0f) + __logf(1.0f + __expf(-fabsf(x))) - 0.69314718055994530942f;
}
__device__ __forceinline__ float swishf(float x) {
    return x / (1.0f + __expf(-x));
}

// -------------------------------------------------------------------------
__global__ __launch_bounds__(256) void emb_kernel(const float* __restrict__ tt,
                                                  float* __restrict__ emb, int n) {
    int i = blockIdx.x * blockDim.x + threadIdx.x;
    if (i >= n * 64) return;
    int node = i >> 6, k = i & 63;
    float t = tt[node];
    float coef = __expf((float)k * (-6.9077552789821368f / 63.0f));
    float e = t * coef;
    emb[node * NF + k]      = swishf(__sinf(e));
    emb[node * NF + 64 + k] = swishf(__cosf(e));
}

// -------------------------------------------------------------------------
// MFMA node GEMM (R16-verified): out = f(A @ W (+bias) (+extra)).
template<int MODE>
__global__ void mfma_gemm(const float* A,
                          const float* __restrict__ W,
                          const float* __restrict__ bias,
                          const float* extra,
                          float* out, int n) {
    __shared__ __align__(16) char A_lds[64 * 256];   // [64 rows][128 k] fp16 swizzled
    const int tid  = threadIdx.x;
    const int wid  = tid >> 6;
    const int lane = tid & 63;
    const int l15  = lane & 15;
    const int lhi  = lane >> 4;

    f16x8 wfr[2][4];
    float bc[2];
    #pragma unroll
    for (int ct = 0; ct < 2; ct++) {
        const int col = (2 * wid + ct) * 16 + l15;
        bc[ct] = (MODE != 0) ? bias[col] : 0.0f;
        #pragma unroll
        for (int t = 0; t < 4; t++)
            #pragma unroll
            for (int j = 0; j < 8; j++) {
                int k = t * 32 + lhi * 8 + j;
                wfr[ct][t][j] = (_Float16)W[k * NF + col];
            }
    }

    const int ntile = (n + 63) >> 6;
    for (int tile = blockIdx.x; tile < ntile; tile += gridDim.x) {
        const int base = tile << 6;
        __syncthreads();
        {
            int row = tid >> 2, part = tid & 3;
            int grow = base + row;
            bool val = grow < n;
            const float* ap = A + (size_t)grow * NF + part * 32;
            #pragma unroll
            for (int kk = 0; kk < 32; kk += 4) {
                float4 v = val ? ld4(ap + kk) : make_float4(0.f, 0.f, 0.f, 0.f);
                int k = part * 32 + kk;
                f16x2 p0; p0[0] = (_Float16)v.x; p0[1] = (_Float16)v.y;
                f16x2 p1; p1[0] = (_Float16)v.z; p1[1] = (_Float16)v.w;
                *(f16x2*)(A_lds + row * 256 + ((2 * k)       ^ ((row & 7) << 4))) = p0;
                *(f16x2*)(A_lds + row * 256 + ((2 * (k + 2)) ^ ((row & 7) << 4))) = p1;
            }
        }
        __syncthreads();

        f32x4 acc[4][2];
        #pragma unroll
        for (int m = 0; m < 4; m++) {
            #pragma unroll
            for (int ct = 0; ct < 2; ct++) {
                f32x4 b = {bc[ct], bc[ct], bc[ct], bc[ct]};
                acc[m][ct] = b;
            }
            const int row = m * 16 + l15;
            #pragma unroll
            for (int t2 = 0; t2 < 4; t2++) {
                int o = row * 256 + ((t2 * 64 + lhi * 16) ^ ((row & 7) << 4));
                f16x8 a = *(const f16x8*)(A_lds + o);
                #pragma unroll
                for (int ct = 0; ct < 2; ct++)
                    acc[m][ct] = __builtin_amdgcn_mfma_f32_16x16x32_f16(a, wfr[ct][t2], acc[m][ct], 0, 0, 0);
            }
        }

        #pragma unroll
        for (int m = 0; m < 4; m++) {
            #pragma unroll
            for (int ct = 0; ct < 2; ct++) {
                const int col = (2 * wid + ct) * 16 + l15;
                #pragma unroll
                for (int r = 0; r < 4; r++) {
                    int grow = base + m * 16 + lhi * 4 + r;
                    if (grow >= n) continue;
                    float v = acc[m][ct][r];
                    if (MODE == 2) v += extra[(size_t)grow * NF + col];
                    if (MODE == 1 || MODE == 2) v = sspf(v);
                    out[(size_t)grow * NF + col] = v;
                }
            }
        }
    }
}

// -------------------------------------------------------------------------
// CSR build: degree -> 3-phase multi-block exclusive scan -> scatter.
__global__ __launch_bounds__(256) void deg_kernel(const int* __restrict__ ei,
                                                  int* __restrict__ deg, int E_) {
    int e = blockIdx.x * blockDim.x + threadIdx.x;
    if (e < E_) atomicAdd(&deg[ei[E_ + e]], 1);
}

__global__ __launch_bounds__(256) void scan_chunk(const int* __restrict__ deg,
                                                  int* __restrict__ csum, int n) {
    int base = blockIdx.x * SCH;
    int s = 0;
    for (int i = threadIdx.x; i < SCH; i += 256) {
        int idx = base + i;
        if (idx < n) s += deg[idx];
    }
    __shared__ int red[4];
    #pragma unroll
    for (int d = 1; d < 64; d <<= 1) s += __shfl_xor(s, d);
    if ((threadIdx.x & 63) == 0) red[threadIdx.x >> 6] = s;
    __syncthreads();
    if (threadIdx.x == 0) csum[blockIdx.x] = red[0] + red[1] + red[2] + red[3];
}

__global__ __launch_bounds__(1024) void scan_csum_k(const int* __restrict__ csum,
                                                    int* __restrict__ coff, int nch,
                                                    int* __restrict__ off, int n, int E_) {
    __shared__ int sm[1024];
    const int tid = threadIdx.x;
    int v = (tid < nch) ? csum[tid] : 0;
    sm[tid] = v;
    __syncthreads();
    for (int st = 1; st < 1024; st <<= 1) {
        int t = (tid >= st) ? sm[tid - st] : 0;
        __syncthreads();
        sm[tid] += t;
        __syncthreads();
    }
    if (tid < nch) coff[tid] = sm[tid] - v;   // exclusive
    if (tid == 0) off[n] = E_;                // total degree == E
}

__global__ __launch_bounds__(256) void scan_emit(const int* __restrict__ deg,
                                                 const int* __restrict__ coff,
                                                 int* __restrict__ off, int n) {
    const int base = blockIdx.x * SCH + threadIdx.x * 8;
    int vals[8]; int s = 0;
    #pragma unroll
    for (int j = 0; j < 8; j++) {
        int idx = base + j;
        vals[j] = (idx < n) ? deg[idx] : 0;
        s += vals[j];
    }
    __shared__ int ts[256];
    ts[threadIdx.x] = s;
    __syncthreads();
    for (int st = 1; st < 256; st <<= 1) {
        int t = (threadIdx.x >= st) ? ts[threadIdx.x - st] : 0;
        __syncthreads();
        ts[threadIdx.x] += t;
        __syncthreads();
    }
    int prefix = coff[blockIdx.x] + ts[threadIdx.x] - s;
    #pragma unroll
    for (int j = 0; j < 8; j++) {
        int idx = base + j;
        if (idx < n) off[idx] = prefix;
        prefix += vals[j];
    }
}

__global__ __launch_bounds__(256) void scatter_kernel(const int* __restrict__ ei,
                                                      const float* __restrict__ elen,
                                                      const int* __restrict__ off,
                                                      int* __restrict__ cur,
                                                      int* __restrict__ perm,
                                                      int* __restrict__ srcp,
                                                      float* __restrict__ Cp, int E_) {
    int e = blockIdx.x * blockDim.x + threadIdx.x;
    if (e < E_) {
        int d = ei[E_ + e];
        int p = off[d] + atomicAdd(&cur[d], 1);
        perm[p] = e;
        srcp[p] = ei[e];
        float len = elen[e];
        float c = 0.5f * (__cosf(len * (PI_F / CUTOFF)) + 1.0f);
        Cp[p] = (len <= CUTOFF && len >= 0.0f) ? c : 0.0f;
    }
}

// tnlo[t] = first node n with off[n] >= 64*t (tile ownership table)
__global__ __launch_bounds__(256) void tilebnd_kernel(const int* __restrict__ off,
                                                      int* __restrict__ tnlo,
                                                      int nN, int ntiles) {
    int t = blockIdx.x * blockDim.x + threadIdx.x;
    if (t > ntiles) return;
    if (t == ntiles) { tnlo[t] = nN; return; }
    int key = t * ET;
    int lo = 0, hi = nN + 1;
    while (lo < hi) { int mid = (lo + hi) >> 1; if (off[mid] < key) lo = mid + 1; else hi = mid; }
    tnlo[t] = lo;
}

// -------------------------------------------------------------------------
// wf_kernel — 512 threads / 8 waves, ONE 16-col ct-tile per wave.
// Halves per-thread register state (w1f 8 + w2f 16 VGPR + acc 16 AGPR)
// -> (512,4) cap 128 fits -> ~2x resident waves vs R16's (256,3).
// Layout math byte-identical to the verified 256-thread version.
__global__ __launch_bounds__(512, 4) void wf_kernel(const float* __restrict__ eattr,
                                                    const float* __restrict__ em1w,
                                                    const float* __restrict__ em1b,
                                                    const float* __restrict__ em2w,
                                                    const float* __restrict__ em2b,
                                                    const int* __restrict__ perm,
                                                    const float* __restrict__ Cp,
                                                    unsigned int* __restrict__ wmsg32,
                                                    int E_) {
    __shared__ __align__(16) char U[ET * 128 + ET * 256];
    __shared__ float C_sm[ET];
    char* ea_p  = U;               // [64][64k] fp16 swizzled
    char* h_p   = U + ET * 128;    // [64][128ch] fp16 swizzled
    char* msg_b = U;               // [64] rows x 264B (132 fp16), overlays ea/h

    const int tid  = threadIdx.x;
    const int wid  = tid >> 6;     // wave 0..7 -> column tile (16 ch)
    const int lane = tid & 63;
    const int l15  = lane & 15;
    const int lhi  = lane >> 4;
    const int col  = wid * 16 + l15;

    f16x8 w1f[2];
    f16x8 w2f[4];
    const float b1c = em1b[col];
    const float b2c = em2b[col];
    #pragma unroll
    for (int t = 0; t < 2; t++)
        #pragma unroll
        for (int j = 0; j < 8; j++) {
            int k = t * 32 + lhi * 8 + j;
            w1f[t][j] = (_Float16)((k < EC) ? em1w[k * NF + col] : 0.0f);
        }
    #pragma unroll
    for (int t = 0; t < 4; t++)
        #pragma unroll
        for (int j = 0; j < 8; j++) {
            int k = t * 32 + lhi * 8 + j;
            w2f[t][j] = (_Float16)em2w[k * NF + col];
        }

    const int ntiles = (E_ + ET - 1) / ET;
    for (int tile = blockIdx.x; tile < ntiles; tile += gridDim.x) {
        const int base = tile * ET;
        const int ec = min(ET, E_ - base);
        const int mmax = (ec + 15) >> 4;
        __syncthreads();   // prev copy done

        if (tid < ET) C_sm[tid] = (tid < ec) ? Cp[base + tid] : 0.0f;
        // stage ea: row = tid>>3 (0..63), part = tid&7, 8 k's (4 f16x2 stores)
        {
            int row = tid >> 3, part = tid & 7;
            bool val = row < ec;
            const float* ep = eattr + (size_t)(val ? perm[base + row] : 0) * EC;
            #pragma unroll
            for (int kk = 0; kk < 8; kk += 2) {
                int k = part * 8 + kk;
                float2 v = make_float2(0.f, 0.f);
                if (val && k <= 48) v = *(const float2*)(ep + k);
                f16x2 pk;
                pk[0] = (_Float16)v.x; pk[1] = (_Float16)v.y;
                *(f16x2*)(ea_p + row * 128 + ((2 * k) ^ ((row & 7) << 4))) = pk;
            }
        }
        __syncthreads();

        // layer 1: h = ssp(ea @ em1 + b1)
        f32x4 acc[4];
        #pragma unroll
        for (int m = 0; m < 4; m++) {
            if (m < mmax) {
                f32x4 b = {b1c, b1c, b1c, b1c};
                acc[m] = b;
                const int row = m * 16 + l15;
                #pragma unroll
                for (int t1 = 0; t1 < 2; t1++) {
                    int o = row * 128 + ((t1 * 64 + lhi * 16) ^ ((row & 7) << 4));
                    f16x8 a = *(const f16x8*)(ea_p + o);
                    acc[m] = __builtin_amdgcn_mfma_f32_16x16x32_f16(a, w1f[t1], acc[m], 0, 0, 0);
                }
            }
        }
        #pragma unroll
        for (int m = 0; m < 4; m++) {
            if (m < mmax) {
                #pragma unroll
                for (int r = 0; r < 4; r++) {
                    int row = m * 16 + lhi * 4 + r;
                    *(_Float16*)(h_p + row * 256 + ((2 * col) ^ ((row & 7) << 4))) =
                        (_Float16)sspf(acc[m][r]);
                }
            }
        }
        __syncthreads();

        // layer 2: wf = h @ em2 + b2
        #pragma unroll
        for (int m = 0; m < 4; m++) {
            if (m < mmax) {
                f32x4 b = {b2c, b2c, b2c, b2c};
                acc[m] = b;
                const int row = m * 16 + l15;
                #pragma unroll
                for (int t2 = 0; t2 < 4; t2++) {
                    int o = row * 256 + ((t2 * 64 + lhi * 16) ^ ((row & 7) << 4));
                    f16x8 a = *(const f16x8*)(h_p + o);
                    acc[m] = __builtin_amdgcn_mfma_f32_16x16x32_f16(a, w2f[t2], acc[m], 0, 0, 0);
                }
            }
        }
        __syncthreads();   // h reads done; msg overlays ea/h

        #pragma unroll
        for (int m = 0; m < 4; m++) {
            if (m < mmax) {
                #pragma unroll
                for (int r = 0; r < 4; r++) {
                    int e = m * 16 + lhi * 4 + r;
                    *(_Float16*)(msg_b + e * 264 + 2 * col) =
                        (_Float16)(acc[m][r] * C_sm[e]);
                }
            }
        }
        __syncthreads();

        // coalesced LDS -> global copy (non-temporal stream)
        for (int j = tid; j < ec * 64; j += 512)
            __builtin_nontemporal_store(
                *(const unsigned int*)(msg_b + (j >> 6) * 264 + (j & 63) * 4),
                &wmsg32[(size_t)base * 64 + j]);
    }
}

// -------------------------------------------------------------------------
// red_conv — pure gather-reduce (R15-verified).
__global__ __launch_bounds__(256) void red_conv(const float* __restrict__ y,
                                                const unsigned int* __restrict__ wmsg32,
                                                const int* __restrict__ srcp,
                                                const int* __restrict__ off,
                                                const int* __restrict__ tnlo,
                                                float* __restrict__ agg,
                                                int ntiles) {
    const int wid  = threadIdx.x >> 6;
    const int lane = threadIdx.x & 63;
    const int c2   = lane * 2;

    for (int tile = blockIdx.x; tile < ntiles; tile += gridDim.x) {
        const int n_lo = tnlo[tile], n_hi1 = tnlo[tile + 1];
        for (int n = n_lo + wid; n < n_hi1; n += 4) {
            float2 a = make_float2(0.f, 0.f);
            int i = off[n];
            const int e1 = off[n + 1];
            for (; i + 4 <= e1; i += 4) {
                int s0 = srcp[i], s1 = srcp[i + 1], s2 = srcp[i + 2], s3 = srcp[i + 3];
                unsigned int u0 = __builtin_nontemporal_load(&wmsg32[(size_t)(i    ) * 64 + lane]);
                unsigned int u1 = __builtin_nontemporal_load(&wmsg32[(size_t)(i + 1) * 64 + lane]);
                unsigned int u2 = __builtin_nontemporal_load(&wmsg32[(size_t)(i + 2) * 64 + lane]);
                unsigned int u3 = __builtin_nontemporal_load(&wmsg32[(size_t)(i + 3) * 64 + lane]);
                float2 y0 = *(const float2*)(y + (size_t)s0 * NF + c2);
                float2 y1 = *(const float2*)(y + (size_t)s1 * NF + c2);
                float2 y2 = *(const float2*)(y + (size_t)s2 * NF + c2);
                float2 y3 = *(const float2*)(y + (size_t)s3 * NF + c2);
                f16x2 m0 = *(const f16x2*)&u0, m1 = *(const f16x2*)&u1;
                f16x2 m2 = *(const f16x2*)&u2, m3 = *(const f16x2*)&u3;
                a.x = fmaf((float)m0[0], y0.x, a.x); a.y = fmaf((float)m0[1], y0.y, a.y);
                a.x = fmaf((float)m1[0], y1.x, a.x); a.y = fmaf((float)m1[1], y1.y, a.y);
                a.x = fmaf((float)m2[0], y2.x, a.x); a.y = fmaf((float)m2[1], y2.y, a.y);
                a.x = fmaf((float)m3[0], y3.x, a.x); a.y = fmaf((float)m3[1], y3.y, a.y);
            }
            for (; i < e1; i++) {
                unsigned int u = __builtin_nontemporal_load(&wmsg32[(size_t)i * 64 + lane]);
                f16x2 mp = *(const f16x2*)&u;
                float2 yv = *(const float2*)(y + (size_t)srcp[i] * NF + c2);
                a.x = fmaf((float)mp[0], yv.x, a.x);
                a.y = fmaf((float)mp[1], yv.y, a.y);
            }
            *(float2*)(agg + (size_t)n * NF + c2) = a;
        }
    }
}

// -------------------------------------------------------------------------
extern "C" void kernel_launch(void* const* d_in, const int* in_sizes, int n_in,
                              void* d_out, int out_size, void* d_ws, size_t ws_size,
                              hipStream_t stream) {
    const float* tt    = (const float*)d_in[0];
    const float* xx    = (const float*)d_in[1];
    const int*   ei    = (const int*)d_in[2];
    const float* elen  = (const float*)d_in[3];
    const float* eattr = (const float*)d_in[4];
    const float* em1w  = (const float*)d_in[5];
    const float* em1b  = (const float*)d_in[6];
    const float* em2w  = (const float*)d_in[7];
    const float* em2b  = (const float*)d_in[8];
    const float* c1m1w = (const float*)d_in[9];
    const float* c1m2w = (const float*)d_in[10];
    const float* c1m2b = (const float*)d_in[11];
    const float* c2m1w = (const float*)d_in[12];
    const float* c2m2w = (const float*)d_in[13];
    const float* c2m2b = (const float*)d_in[14];
    const float* tew   = (const float*)d_in[15];
    const float* teb   = (const float*)d_in[16];
    const float* linw  = (const float*)d_in[17];
    const float* linb  = (const float*)d_in[18];

    const int n  = in_sizes[0];
    const int E_ = in_sizes[2] / 2;
    const int ntiles = (E_ + ET - 1) / ET;
    const int gtiles = (n + 63) >> 6;
    const int nch = (n + SCH - 1) / SCH;
    float* out = (float*)d_out;

    const size_t NB = (size_t)n * NF;
    float* B0 = (float*)d_ws;   // y1 / y2 / x3
    float* B1 = B0 + NB;        // agg
    float* B2 = B1 + NB;        // emb -> t (in-place) -> x_mid
    int* off  = (int*)(B2 + NB);      // n+1
    int* perm = off + (n + 1);        // E
    int* deg  = perm + E_;            // n
    int* cur  = deg + n;              // n
    int* srcp = cur + n;              // E
    int* tnlo = srcp + E_;            // ntiles+1
    int* csum = tnlo + ntiles + 1;    // nch
    int* coff = csum + nch;           // nch
    float* Cp = (float*)(coff + nch); // E
    unsigned int* wmsg32 = (unsigned int*)(Cp + E_);   // E*64 u32

    // ---- CSR build (multi-block scan) + ownership table
    hipMemsetAsync(deg, 0, (size_t)2 * n * sizeof(int), stream);
    deg_kernel<<<(E_ + 255) / 256, 256, 0, stream>>>(ei, deg, E_);
    scan_chunk<<<nch, 256, 0, stream>>>(deg, csum, n);
    scan_csum_k<<<1, 1024, 0, stream>>>(csum, coff, nch, off, n, E_);
    scan_emit<<<nch, 256, 0, stream>>>(deg, coff, off, n);
    scatter_kernel<<<(E_ + 255) / 256, 256, 0, stream>>>(ei, elen, off, cur,
                                                         perm, srcp, Cp, E_);
    tilebnd_kernel<<<(ntiles + 256) / 256, 256, 0, stream>>>(off, tnlo, n, ntiles);

    // emb -> B2 ; t = swish_emb @ te_w + te_b -> B2 (in-place safe)
    emb_kernel<<<(n * 64 + 255) / 256, 256, 0, stream>>>(tt, B2, n);
    mfma_gemm<3><<<gtiles, 256, 0, stream>>>(B2, tew, teb, nullptr, B2, n);

    // msg = Wf*C (conv-invariant) computed ONCE
    wf_kernel<<<1280, 512, 0, stream>>>(eattr, em1w, em1b, em2w, em2b,
                                        perm, Cp, wmsg32, E_);

    // y1 = xx @ c1_m1w -> B0
    mfma_gemm<0><<<gtiles, 256, 0, stream>>>(xx, c1m1w, nullptr, nullptr, B0, n);

    // conv1 -> B1
    red_conv<<<4096, 256, 0, stream>>>(B0, wmsg32, srcp, off, tnlo, B1, ntiles);

    // x_mid = ssp(agg @ c1_m2w + b + t) -> B2 (extra==out elementwise-safe)
    mfma_gemm<2><<<gtiles, 256, 0, stream>>>(B1, c1m2w, c1m2b, B2, B2, n);

    // y2 = x_mid @ c2_m1w -> B0
    mfma_gemm<0><<<gtiles, 256, 0, stream>>>(B2, c2m1w, nullptr, nullptr, B0, n);

    // conv2 -> B1
    red_conv<<<4096, 256, 0, stream>>>(B0, wmsg32, srcp, off, tnlo, B1, ntiles);

    // x3 = ssp(agg @ c2_m2w + b) -> B0 ; out = ssp(x3 @ lin_w + b) -> d_out
    mfma_gemm<1><<<gtiles, 256, 0, stream>>>(B1, c2m2w, c2m2b, nullptr, B0, n);
    mfma_gemm<1><<<gtiles, 256, 0, stream>>>(B0, linw, linb, nullptr, out, n);
}

// Round 18
// 541.965 us; speedup vs baseline: 1.5429x; 1.1731x over previous
//
#include <hip/hip_runtime.h>
#include <hip/hip_bf16.h>
#include <math.h>

#define NF 128
#define EC 50
#define ET 64              // edges per MFMA tile/pass
#define SCH 2048           // scan chunk size
#define CUTOFF 0.8f
#define PI_F 3.14159265358979323846f

typedef __attribute__((ext_vector_type(8))) _Float16 f16x8;
typedef __attribute__((ext_vector_type(2))) _Float16 f16x2;
typedef __attribute__((ext_vector_type(4))) float f32x4;

__device__ __forceinline__ float4 ld4(const float* p) { return *reinterpret_cast<const float4*>(p); }

// fast ssp: hardware exp/log; validated R7-R17 (absmax <= 0.0078)
__device__ __forceinline__ float sspf(float x) {
    return fmaxf(x, 0.0f) + __logf(1.0f + __expf(-fabsf(x))) - 0.69314718055994530942f;
}
__device__ __forceinline__ float swishf(float x) {
    return x / (1.0f + __expf(-x));
}

// -------------------------------------------------------------------------
// emb -> fp16 B2
__global__ __launch_bounds__(256) void emb_kernel(const float* __restrict__ tt,
                                                  _Float16* __restrict__ emb, int n) {
    int i = blockIdx.x * blockDim.x + threadIdx.x;
    if (i >= n * 64) return;
    int node = i >> 6, k = i & 63;
    float t = tt[node];
    float coef = __expf((float)k * (-6.9077552789821368f / 63.0f));
    float e = t * coef;
    emb[node * NF + k]      = (_Float16)swishf(__sinf(e));
    emb[node * NF + 64 + k] = (_Float16)swishf(__cosf(e));
}

// -------------------------------------------------------------------------
// MFMA node GEMM (R16-verified fragments): out = f(A @ W (+bias) (+extra)).
// A16/O16 select fp16 vs f32 for A-input / output buffers; extra is fp16.
// MODE 0: plain. MODE 1: ssp(.+b). MODE 2: ssp(.+b+extra). MODE 3: .+b
// In-place safe: tile staged to LDS + barrier before stores; extra==out
// read-before-write per thread.
template<int MODE, int A16, int O16>
__global__ void mfma_gemm(const void* __restrict__ Av,
                          const float* __restrict__ W,
                          const float* __restrict__ bias,
                          const _Float16* extra,
                          void* outv, int n) {
    __shared__ __align__(16) char A_lds[64 * 256];   // [64 rows][128 k] fp16 swizzled
    const int tid  = threadIdx.x;
    const int wid  = tid >> 6;
    const int lane = tid & 63;
    const int l15  = lane & 15;
    const int lhi  = lane >> 4;

    f16x8 wfr[2][4];
    float bc[2];
    #pragma unroll
    for (int ct = 0; ct < 2; ct++) {
        const int col = (2 * wid + ct) * 16 + l15;
        bc[ct] = (MODE != 0) ? bias[col] : 0.0f;
        #pragma unroll
        for (int t = 0; t < 4; t++)
            #pragma unroll
            for (int j = 0; j < 8; j++) {
                int k = t * 32 + lhi * 8 + j;
                wfr[ct][t][j] = (_Float16)W[k * NF + col];
            }
    }

    const int ntile = (n + 63) >> 6;
    for (int tile = blockIdx.x; tile < ntile; tile += gridDim.x) {
        const int base = tile << 6;
        __syncthreads();
        // stage A tile -> fp16 swizzled LDS (row = tid>>2, 32 k's per thread)
        {
            int row = tid >> 2, part = tid & 3;
            int grow = base + row;
            bool val = grow < n;
            if (A16) {
                const _Float16* ap = (const _Float16*)Av + (size_t)grow * NF + part * 32;
                #pragma unroll
                for (int kk = 0; kk < 32; kk += 8) {
                    uint4 v = val ? *(const uint4*)(ap + kk)
                                  : make_uint4(0u, 0u, 0u, 0u);
                    int k = part * 32 + kk;
                    *(unsigned*)(A_lds + row * 256 + ((2 * (k + 0)) ^ ((row & 7) << 4))) = v.x;
                    *(unsigned*)(A_lds + row * 256 + ((2 * (k + 2)) ^ ((row & 7) << 4))) = v.y;
                    *(unsigned*)(A_lds + row * 256 + ((2 * (k + 4)) ^ ((row & 7) << 4))) = v.z;
                    *(unsigned*)(A_lds + row * 256 + ((2 * (k + 6)) ^ ((row & 7) << 4))) = v.w;
                }
            } else {
                const float* ap = (const float*)Av + (size_t)grow * NF + part * 32;
                #pragma unroll
                for (int kk = 0; kk < 32; kk += 4) {
                    float4 v = val ? ld4(ap + kk) : make_float4(0.f, 0.f, 0.f, 0.f);
                    int k = part * 32 + kk;
                    f16x2 p0; p0[0] = (_Float16)v.x; p0[1] = (_Float16)v.y;
                    f16x2 p1; p1[0] = (_Float16)v.z; p1[1] = (_Float16)v.w;
                    *(f16x2*)(A_lds + row * 256 + ((2 * k)       ^ ((row & 7) << 4))) = p0;
                    *(f16x2*)(A_lds + row * 256 + ((2 * (k + 2)) ^ ((row & 7) << 4))) = p1;
                }
            }
        }
        __syncthreads();

        f32x4 acc[4][2];
        #pragma unroll
        for (int m = 0; m < 4; m++) {
            #pragma unroll
            for (int ct = 0; ct < 2; ct++) {
                f32x4 b = {bc[ct], bc[ct], bc[ct], bc[ct]};
                acc[m][ct] = b;
            }
            const int row = m * 16 + l15;
            #pragma unroll
            for (int t2 = 0; t2 < 4; t2++) {
                int o = row * 256 + ((t2 * 64 + lhi * 16) ^ ((row & 7) << 4));
                f16x8 a = *(const f16x8*)(A_lds + o);
                #pragma unroll
                for (int ct = 0; ct < 2; ct++)
                    acc[m][ct] = __builtin_amdgcn_mfma_f32_16x16x32_f16(a, wfr[ct][t2], acc[m][ct], 0, 0, 0);
            }
        }

        // epilogue: D row = m*16+lhi*4+r, col = (2wid+ct)*16+l15
        #pragma unroll
        for (int m = 0; m < 4; m++) {
            #pragma unroll
            for (int ct = 0; ct < 2; ct++) {
                const int col = (2 * wid + ct) * 16 + l15;
                #pragma unroll
                for (int r = 0; r < 4; r++) {
                    int grow = base + m * 16 + lhi * 4 + r;
                    if (grow >= n) continue;
                    float v = acc[m][ct][r];
                    if (MODE == 2) v += (float)extra[(size_t)grow * NF + col];
                    if (MODE == 1 || MODE == 2) v = sspf(v);
                    if (O16)
                        ((_Float16*)outv)[(size_t)grow * NF + col] = (_Float16)v;
                    else
                        ((float*)outv)[(size_t)grow * NF + col] = v;
                }
            }
        }
    }
}

// -------------------------------------------------------------------------
// CSR build: degree -> 3-phase multi-block exclusive scan -> scatter.
__global__ __launch_bounds__(256) void deg_kernel(const int* __restrict__ ei,
                                                  int* __restrict__ deg, int E_) {
    int e = blockIdx.x * blockDim.x + threadIdx.x;
    if (e < E_) atomicAdd(&deg[ei[E_ + e]], 1);
}

__global__ __launch_bounds__(256) void scan_chunk(const int* __restrict__ deg,
                                                  int* __restrict__ csum, int n) {
    int base = blockIdx.x * SCH;
    int s = 0;
    for (int i = threadIdx.x; i < SCH; i += 256) {
        int idx = base + i;
        if (idx < n) s += deg[idx];
    }
    __shared__ int red[4];
    #pragma unroll
    for (int d = 1; d < 64; d <<= 1) s += __shfl_xor(s, d);
    if ((threadIdx.x & 63) == 0) red[threadIdx.x >> 6] = s;
    __syncthreads();
    if (threadIdx.x == 0) csum[blockIdx.x] = red[0] + red[1] + red[2] + red[3];
}

__global__ __launch_bounds__(1024) void scan_csum_k(const int* __restrict__ csum,
                                                    int* __restrict__ coff, int nch,
                                                    int* __restrict__ off, int n, int E_) {
    __shared__ int sm[1024];
    const int tid = threadIdx.x;
    int v = (tid < nch) ? csum[tid] : 0;
    sm[tid] = v;
    __syncthreads();
    for (int st = 1; st < 1024; st <<= 1) {
        int t = (tid >= st) ? sm[tid - st] : 0;
        __syncthreads();
        sm[tid] += t;
        __syncthreads();
    }
    if (tid < nch) coff[tid] = sm[tid] - v;   // exclusive
    if (tid == 0) off[n] = E_;                // total degree == E
}

__global__ __launch_bounds__(256) void scan_emit(const int* __restrict__ deg,
                                                 const int* __restrict__ coff,
                                                 int* __restrict__ off, int n) {
    const int base = blockIdx.x * SCH + threadIdx.x * 8;
    int vals[8]; int s = 0;
    #pragma unroll
    for (int j = 0; j < 8; j++) {
        int idx = base + j;
        vals[j] = (idx < n) ? deg[idx] : 0;
        s += vals[j];
    }
    __shared__ int ts[256];
    ts[threadIdx.x] = s;
    __syncthreads();
    for (int st = 1; st < 256; st <<= 1) {
        int t = (threadIdx.x >= st) ? ts[threadIdx.x - st] : 0;
        __syncthreads();
        ts[threadIdx.x] += t;
        __syncthreads();
    }
    int prefix = coff[blockIdx.x] + ts[threadIdx.x] - s;
    #pragma unroll
    for (int j = 0; j < 8; j++) {
        int idx = base + j;
        if (idx < n) off[idx] = prefix;
        prefix += vals[j];
    }
}

__global__ __launch_bounds__(256) void scatter_kernel(const int* __restrict__ ei,
                                                      const float* __restrict__ elen,
                                                      const int* __restrict__ off,
                                                      int* __restrict__ cur,
                                                      int* __restrict__ perm,
                                                      int* __restrict__ srcp,
                                                      float* __restrict__ Cp, int E_) {
    int e = blockIdx.x * blockDim.x + threadIdx.x;
    if (e < E_) {
        int d = ei[E_ + e];
        int p = off[d] + atomicAdd(&cur[d], 1);
        perm[p] = e;
        srcp[p] = ei[e];
        float len = elen[e];
        float c = 0.5f * (__cosf(len * (PI_F / CUTOFF)) + 1.0f);
        Cp[p] = (len <= CUTOFF && len >= 0.0f) ? c : 0.0f;
    }
}

// tnlo[t] = first node n with off[n] >= 64*t (tile ownership table)
__global__ __launch_bounds__(256) void tilebnd_kernel(const int* __restrict__ off,
                                                      int* __restrict__ tnlo,
                                                      int nN, int ntiles) {
    int t = blockIdx.x * blockDim.x + threadIdx.x;
    if (t > ntiles) return;
    if (t == ntiles) { tnlo[t] = nN; return; }
    int key = t * ET;
    int lo = 0, hi = nN + 1;
    while (lo < hi) { int mid = (lo + hi) >> 1; if (off[mid] < key) lo = mid + 1; else hi = mid; }
    tnlo[t] = lo;
}

// -------------------------------------------------------------------------
// wf_kernel — 512 threads / 8 waves, one 16-col ct-tile per wave (R17).
__global__ __launch_bounds__(512, 4) void wf_kernel(const float* __restrict__ eattr,
                                                    const float* __restrict__ em1w,
                                                    const float* __restrict__ em1b,
                                                    const float* __restrict__ em2w,
                                                    const float* __restrict__ em2b,
                                                    const int* __restrict__ perm,
                                                    const float* __restrict__ Cp,
                                                    unsigned int* __restrict__ wmsg32,
                                                    int E_) {
    __shared__ __align__(16) char U[ET * 128 + ET * 256];
    __shared__ float C_sm[ET];
    char* ea_p  = U;               // [64][64k] fp16 swizzled
    char* h_p   = U + ET * 128;    // [64][128ch] fp16 swizzled
    char* msg_b = U;               // [64] rows x 264B (132 fp16), overlays ea/h

    const int tid  = threadIdx.x;
    const int wid  = tid >> 6;     // wave 0..7 -> column tile (16 ch)
    const int lane = tid & 63;
    const int l15  = lane & 15;
    const int lhi  = lane >> 4;
    const int col  = wid * 16 + l15;

    f16x8 w1f[2];
    f16x8 w2f[4];
    const float b1c = em1b[col];
    const float b2c = em2b[col];
    #pragma unroll
    for (int t = 0; t < 2; t++)
        #pragma unroll
        for (int j = 0; j < 8; j++) {
            int k = t * 32 + lhi * 8 + j;
            w1f[t][j] = (_Float16)((k < EC) ? em1w[k * NF + col] : 0.0f);
        }
    #pragma unroll
    for (int t = 0; t < 4; t++)
        #pragma unroll
        for (int j = 0; j < 8; j++) {
            int k = t * 32 + lhi * 8 + j;
            w2f[t][j] = (_Float16)em2w[k * NF + col];
        }

    const int ntiles = (E_ + ET - 1) / ET;
    for (int tile = blockIdx.x; tile < ntiles; tile += gridDim.x) {
        const int base = tile * ET;
        const int ec = min(ET, E_ - base);
        const int mmax = (ec + 15) >> 4;
        __syncthreads();   // prev copy done

        if (tid < ET) C_sm[tid] = (tid < ec) ? Cp[base + tid] : 0.0f;
        {
            int row = tid >> 3, part = tid & 7;
            bool val = row < ec;
            const float* ep = eattr + (size_t)(val ? perm[base + row] : 0) * EC;
            #pragma unroll
            for (int kk = 0; kk < 8; kk += 2) {
                int k = part * 8 + kk;
                float2 v = make_float2(0.f, 0.f);
                if (val && k <= 48) v = *(const float2*)(ep + k);
                f16x2 pk;
                pk[0] = (_Float16)v.x; pk[1] = (_Float16)v.y;
                *(f16x2*)(ea_p + row * 128 + ((2 * k) ^ ((row & 7) << 4))) = pk;
            }
        }
        __syncthreads();

        // layer 1: h = ssp(ea @ em1 + b1)
        f32x4 acc[4];
        #pragma unroll
        for (int m = 0; m < 4; m++) {
            if (m < mmax) {
                f32x4 b = {b1c, b1c, b1c, b1c};
                acc[m] = b;
                const int row = m * 16 + l15;
                #pragma unroll
                for (int t1 = 0; t1 < 2; t1++) {
                    int o = row * 128 + ((t1 * 64 + lhi * 16) ^ ((row & 7) << 4));
                    f16x8 a = *(const f16x8*)(ea_p + o);
                    acc[m] = __builtin_amdgcn_mfma_f32_16x16x32_f16(a, w1f[t1], acc[m], 0, 0, 0);
                }
            }
        }
        #pragma unroll
        for (int m = 0; m < 4; m++) {
            if (m < mmax) {
                #pragma unroll
                for (int r = 0; r < 4; r++) {
                    int row = m * 16 + lhi * 4 + r;
                    *(_Float16*)(h_p + row * 256 + ((2 * col) ^ ((row & 7) << 4))) =
                        (_Float16)sspf(acc[m][r]);
                }
            }
        }
        __syncthreads();

        // layer 2: wf = h @ em2 + b2
        #pragma unroll
        for (int m = 0; m < 4; m++) {
            if (m < mmax) {
                f32x4 b = {b2c, b2c, b2c, b2c};
                acc[m] = b;
                const int row = m * 16 + l15;
                #pragma unroll
                for (int t2 = 0; t2 < 4; t2++) {
                    int o = row * 256 + ((t2 * 64 + lhi * 16) ^ ((row & 7) << 4));
                    f16x8 a = *(const f16x8*)(h_p + o);
                    acc[m] = __builtin_amdgcn_mfma_f32_16x16x32_f16(a, w2f[t2], acc[m], 0, 0, 0);
                }
            }
        }
        __syncthreads();   // h reads done; msg overlays ea/h

        #pragma unroll
        for (int m = 0; m < 4; m++) {
            if (m < mmax) {
                #pragma unroll
                for (int r = 0; r < 4; r++) {
                    int e = m * 16 + lhi * 4 + r;
                    *(_Float16*)(msg_b + e * 264 + 2 * col) =
                        (_Float16)(acc[m][r] * C_sm[e]);
                }
            }
        }
        __syncthreads();

        // coalesced LDS -> global copy (non-temporal stream)
        for (int j = tid; j < ec * 64; j += 512)
            __builtin_nontemporal_store(
                *(const unsigned int*)(msg_b + (j >> 6) * 264 + (j & 63) * 4),
                &wmsg32[(size_t)base * 64 + j]);
    }
}

// -------------------------------------------------------------------------
// red_conv — pure gather-reduce; fp16 y rows (256B, L2-friendly), fp16 agg.
__global__ __launch_bounds__(256) void red_conv(const unsigned int* __restrict__ y32,
                                                const unsigned int* __restrict__ wmsg32,
                                                const int* __restrict__ srcp,
                                                const int* __restrict__ off,
                                                const int* __restrict__ tnlo,
                                                unsigned int* __restrict__ agg32,
                                                int ntiles) {
    const int wid  = threadIdx.x >> 6;
    const int lane = threadIdx.x & 63;

    for (int tile = blockIdx.x; tile < ntiles; tile += gridDim.x) {
        const int n_lo = tnlo[tile], n_hi1 = tnlo[tile + 1];
        for (int n = n_lo + wid; n < n_hi1; n += 4) {
            float2 a = make_float2(0.f, 0.f);
            int i = off[n];
            const int e1 = off[n + 1];
            for (; i + 4 <= e1; i += 4) {
                int s0 = srcp[i], s1 = srcp[i + 1], s2 = srcp[i + 2], s3 = srcp[i + 3];
                unsigned int u0 = __builtin_nontemporal_load(&wmsg32[(size_t)(i    ) * 64 + lane]);
                unsigned int u1 = __builtin_nontemporal_load(&wmsg32[(size_t)(i + 1) * 64 + lane]);
                unsigned int u2 = __builtin_nontemporal_load(&wmsg32[(size_t)(i + 2) * 64 + lane]);
                unsigned int u3 = __builtin_nontemporal_load(&wmsg32[(size_t)(i + 3) * 64 + lane]);
                unsigned int v0 = y32[(size_t)s0 * 64 + lane];
                unsigned int v1 = y32[(size_t)s1 * 64 + lane];
                unsigned int v2 = y32[(size_t)s2 * 64 + lane];
                unsigned int v3 = y32[(size_t)s3 * 64 + lane];
                f16x2 m0 = *(const f16x2*)&u0, m1 = *(const f16x2*)&u1;
                f16x2 m2 = *(const f16x2*)&u2, m3 = *(const f16x2*)&u3;
                f16x2 q0 = *(const f16x2*)&v0, q1 = *(const f16x2*)&v1;
                f16x2 q2 = *(const f16x2*)&v2, q3 = *(const f16x2*)&v3;
                a.x = fmaf((float)m0[0], (float)q0[0], a.x); a.y = fmaf((float)m0[1], (float)q0[1], a.y);
                a.x = fmaf((float)m1[0], (float)q1[0], a.x); a.y = fmaf((float)m1[1], (float)q1[1], a.y);
                a.x = fmaf((float)m2[0], (float)q2[0], a.x); a.y = fmaf((float)m2[1], (float)q2[1], a.y);
                a.x = fmaf((float)m3[0], (float)q3[0], a.x); a.y = fmaf((float)m3[1], (float)q3[1], a.y);
            }
            for (; i < e1; i++) {
                unsigned int u = __builtin_nontemporal_load(&wmsg32[(size_t)i * 64 + lane]);
                unsigned int v = y32[(size_t)srcp[i] * 64 + lane];
                f16x2 mp = *(const f16x2*)&u;
                f16x2 qv = *(const f16x2*)&v;
                a.x = fmaf((float)mp[0], (float)qv[0], a.x);
                a.y = fmaf((float)mp[1], (float)qv[1], a.y);
            }
            f16x2 o; o[0] = (_Float16)a.x; o[1] = (_Float16)a.y;
            agg32[(size_t)n * 64 + lane] = *(const unsigned int*)&o;
        }
    }
}

// -------------------------------------------------------------------------
extern "C" void kernel_launch(void* const* d_in, const int* in_sizes, int n_in,
                              void* d_out, int out_size, void* d_ws, size_t ws_size,
                              hipStream_t stream) {
    const float* tt    = (const float*)d_in[0];
    const float* xx    = (const float*)d_in[1];
    const int*   ei    = (const int*)d_in[2];
    const float* elen  = (const float*)d_in[3];
    const float* eattr = (const float*)d_in[4];
    const float* em1w  = (const float*)d_in[5];
    const float* em1b  = (const float*)d_in[6];
    const float* em2w  = (const float*)d_in[7];
    const float* em2b  = (const float*)d_in[8];
    const float* c1m1w = (const float*)d_in[9];
    const float* c1m2w = (const float*)d_in[10];
    const float* c1m2b = (const float*)d_in[11];
    const float* c2m1w = (const float*)d_in[12];
    const float* c2m2w = (const float*)d_in[13];
    const float* c2m2b = (const float*)d_in[14];
    const float* tew   = (const float*)d_in[15];
    const float* teb   = (const float*)d_in[16];
    const float* linw  = (const float*)d_in[17];
    const float* linb  = (const float*)d_in[18];

    const int n  = in_sizes[0];
    const int E_ = in_sizes[2] / 2;
    const int ntiles = (E_ + ET - 1) / ET;
    const int gtiles = (n + 63) >> 6;
    const int nch = (n + SCH - 1) / SCH;
    float* out = (float*)d_out;

    // ws layout: fp16 node buffers (3 x NB halfs) then CSR ints + wmsg.
    const size_t NB = (size_t)n * NF;
    _Float16* B0h = (_Float16*)d_ws;   // y1 / y2 / x3   (fp16)
    _Float16* B1h = B0h + NB;          // agg            (fp16)
    _Float16* B2h = B1h + NB;          // emb/t/x_mid    (fp16)
    int* off  = (int*)(B2h + NB);      // n+1
    int* perm = off + (n + 1);         // E
    int* deg  = perm + E_;             // n
    int* cur  = deg + n;               // n
    int* srcp = cur + n;               // E
    int* tnlo = srcp + E_;             // ntiles+1
    int* csum = tnlo + ntiles + 1;     // nch
    int* coff = csum + nch;            // nch
    float* Cp = (float*)(coff + nch);  // E
    unsigned int* wmsg32 = (unsigned int*)(Cp + E_);   // E*64 u32

    // ---- CSR build (multi-block scan) + ownership table
    hipMemsetAsync(deg, 0, (size_t)2 * n * sizeof(int), stream);
    deg_kernel<<<(E_ + 255) / 256, 256, 0, stream>>>(ei, deg, E_);
    scan_chunk<<<nch, 256, 0, stream>>>(deg, csum, n);
    scan_csum_k<<<1, 1024, 0, stream>>>(csum, coff, nch, off, n, E_);
    scan_emit<<<nch, 256, 0, stream>>>(deg, coff, off, n);
    scatter_kernel<<<(E_ + 255) / 256, 256, 0, stream>>>(ei, elen, off, cur,
                                                         perm, srcp, Cp, E_);
    tilebnd_kernel<<<(ntiles + 256) / 256, 256, 0, stream>>>(off, tnlo, n, ntiles);

    // emb -> B2h ; t = swish_emb @ te_w + te_b -> B2h (in-place safe)
    emb_kernel<<<(n * 64 + 255) / 256, 256, 0, stream>>>(tt, B2h, n);
    mfma_gemm<3, 1, 1><<<gtiles, 256, 0, stream>>>(B2h, tew, teb, nullptr, B2h, n);

    // msg = Wf*C (conv-invariant) computed ONCE
    wf_kernel<<<1280, 512, 0, stream>>>(eattr, em1w, em1b, em2w, em2b,
                                        perm, Cp, wmsg32, E_);

    // y1 = xx @ c1_m1w -> B0h   (A = f32 input)
    mfma_gemm<0, 0, 1><<<gtiles, 256, 0, stream>>>(xx, c1m1w, nullptr, nullptr, B0h, n);

    // conv1 -> B1h
    red_conv<<<4096, 256, 0, stream>>>((const unsigned int*)B0h, wmsg32, srcp,
                                       off, tnlo, (unsigned int*)B1h, ntiles);

    // x_mid = ssp(agg @ c1_m2w + b + t) -> B2h (extra==out elementwise-safe)
    mfma_gemm<2, 1, 1><<<gtiles, 256, 0, stream>>>(B1h, c1m2w, c1m2b, B2h, B2h, n);

    // y2 = x_mid @ c2_m1w -> B0h
    mfma_gemm<0, 1, 1><<<gtiles, 256, 0, stream>>>(B2h, c2m1w, nullptr, nullptr, B0h, n);

    // conv2 -> B1h
    red_conv<<<4096, 256, 0, stream>>>((const unsigned int*)B0h, wmsg32, srcp,
                                       off, tnlo, (unsigned int*)B1h, ntiles);

    // x3 = ssp(agg @ c2_m2w + b) -> B0h ; out = ssp(x3 @ lin_w + b) -> d_out (f32)
    mfma_gemm<1, 1, 1><<<gtiles, 256, 0, stream>>>(B1h, c2m2w, c2m2b, nullptr, B0h, n);
    mfma_gemm<1, 1, 0><<<gtiles, 256, 0, stream>>>(B0h, linw, linb, nullptr, out, n);
}

// Round 19
// 529.557 us; speedup vs baseline: 1.5791x; 1.0234x over previous
//
#include <hip/hip_runtime.h>
#include <hip/hip_bf16.h>
#include <math.h>

#define NF 128
#define EC 50
#define ET 64              // node-ownership window (off/tnlo granularity)
#define WT 128             // wf_kernel edges per MFMA tile
#define SCH 2048           // scan chunk size
#define CUTOFF 0.8f
#define PI_F 3.14159265358979323846f

typedef __attribute__((ext_vector_type(8))) _Float16 f16x8;
typedef __attribute__((ext_vector_type(2))) _Float16 f16x2;
typedef __attribute__((ext_vector_type(4))) float f32x4;

__device__ __forceinline__ float4 ld4(const float* p) { return *reinterpret_cast<const float4*>(p); }

// fast ssp: hardware exp/log; validated R7-R18 (absmax <= 0.0078)
__device__ __forceinline__ float sspf(float x) {
    return fmaxf(x, 0.0f) + __logf(1.0f + __expf(-fabsf(x))) - 0.69314718055994530942f;
}
__device__ __forceinline__ float swishf(float x) {
    return x / (1.0f + __expf(-x));
}

// -------------------------------------------------------------------------
// emb -> fp16 B2
__global__ __launch_bounds__(256) void emb_kernel(const float* __restrict__ tt,
                                                  _Float16* __restrict__ emb, int n) {
    int i = blockIdx.x * blockDim.x + threadIdx.x;
    if (i >= n * 64) return;
    int node = i >> 6, k = i & 63;
    float t = tt[node];
    float coef = __expf((float)k * (-6.9077552789821368f / 63.0f));
    float e = t * coef;
    emb[node * NF + k]      = (_Float16)swishf(__sinf(e));
    emb[node * NF + 64 + k] = (_Float16)swishf(__cosf(e));
}

// -------------------------------------------------------------------------
// MFMA node GEMM (R16-verified fragments): out = f(A @ W (+bias) (+extra)).
template<int MODE, int A16, int O16>
__global__ void mfma_gemm(const void* __restrict__ Av,
                          const float* __restrict__ W,
                          const float* __restrict__ bias,
                          const _Float16* extra,
                          void* outv, int n) {
    __shared__ __align__(16) char A_lds[64 * 256];   // [64 rows][128 k] fp16 swizzled
    const int tid  = threadIdx.x;
    const int wid  = tid >> 6;
    const int lane = tid & 63;
    const int l15  = lane & 15;
    const int lhi  = lane >> 4;

    f16x8 wfr[2][4];
    float bc[2];
    #pragma unroll
    for (int ct = 0; ct < 2; ct++) {
        const int col = (2 * wid + ct) * 16 + l15;
        bc[ct] = (MODE != 0) ? bias[col] : 0.0f;
        #pragma unroll
        for (int t = 0; t < 4; t++)
            #pragma unroll
            for (int j = 0; j < 8; j++) {
                int k = t * 32 + lhi * 8 + j;
                wfr[ct][t][j] = (_Float16)W[k * NF + col];
            }
    }

    const int ntile = (n + 63) >> 6;
    for (int tile = blockIdx.x; tile < ntile; tile += gridDim.x) {
        const int base = tile << 6;
        __syncthreads();
        {
            int row = tid >> 2, part = tid & 3;
            int grow = base + row;
            bool val = grow < n;
            if (A16) {
                const _Float16* ap = (const _Float16*)Av + (size_t)grow * NF + part * 32;
                #pragma unroll
                for (int kk = 0; kk < 32; kk += 8) {
                    uint4 v = val ? *(const uint4*)(ap + kk)
                                  : make_uint4(0u, 0u, 0u, 0u);
                    int k = part * 32 + kk;
                    *(unsigned*)(A_lds + row * 256 + ((2 * (k + 0)) ^ ((row & 7) << 4))) = v.x;
                    *(unsigned*)(A_lds + row * 256 + ((2 * (k + 2)) ^ ((row & 7) << 4))) = v.y;
                    *(unsigned*)(A_lds + row * 256 + ((2 * (k + 4)) ^ ((row & 7) << 4))) = v.z;
                    *(unsigned*)(A_lds + row * 256 + ((2 * (k + 6)) ^ ((row & 7) << 4))) = v.w;
                }
            } else {
                const float* ap = (const float*)Av + (size_t)grow * NF + part * 32;
                #pragma unroll
                for (int kk = 0; kk < 32; kk += 4) {
                    float4 v = val ? ld4(ap + kk) : make_float4(0.f, 0.f, 0.f, 0.f);
                    int k = part * 32 + kk;
                    f16x2 p0; p0[0] = (_Float16)v.x; p0[1] = (_Float16)v.y;
                    f16x2 p1; p1[0] = (_Float16)v.z; p1[1] = (_Float16)v.w;
                    *(f16x2*)(A_lds + row * 256 + ((2 * k)       ^ ((row & 7) << 4))) = p0;
                    *(f16x2*)(A_lds + row * 256 + ((2 * (k + 2)) ^ ((row & 7) << 4))) = p1;
                }
            }
        }
        __syncthreads();

        f32x4 acc[4][2];
        #pragma unroll
        for (int m = 0; m < 4; m++) {
            #pragma unroll
            for (int ct = 0; ct < 2; ct++) {
                f32x4 b = {bc[ct], bc[ct], bc[ct], bc[ct]};
                acc[m][ct] = b;
            }
            const int row = m * 16 + l15;
            #pragma unroll
            for (int t2 = 0; t2 < 4; t2++) {
                int o = row * 256 + ((t2 * 64 + lhi * 16) ^ ((row & 7) << 4));
                f16x8 a = *(const f16x8*)(A_lds + o);
                #pragma unroll
                for (int ct = 0; ct < 2; ct++)
                    acc[m][ct] = __builtin_amdgcn_mfma_f32_16x16x32_f16(a, wfr[ct][t2], acc[m][ct], 0, 0, 0);
            }
        }

        #pragma unroll
        for (int m = 0; m < 4; m++) {
            #pragma unroll
            for (int ct = 0; ct < 2; ct++) {
                const int col = (2 * wid + ct) * 16 + l15;
                #pragma unroll
                for (int r = 0; r < 4; r++) {
                    int grow = base + m * 16 + lhi * 4 + r;
                    if (grow >= n) continue;
                    float v = acc[m][ct][r];
                    if (MODE == 2) v += (float)extra[(size_t)grow * NF + col];
                    if (MODE == 1 || MODE == 2) v = sspf(v);
                    if (O16)
                        ((_Float16*)outv)[(size_t)grow * NF + col] = (_Float16)v;
                    else
                        ((float*)outv)[(size_t)grow * NF + col] = v;
                }
            }
        }
    }
}

// -------------------------------------------------------------------------
// CSR build: degree -> 3-phase multi-block exclusive scan -> scatter.
__global__ __launch_bounds__(256) void deg_kernel(const int* __restrict__ ei,
                                                  int* __restrict__ deg, int E_) {
    int e = blockIdx.x * blockDim.x + threadIdx.x;
    if (e < E_) atomicAdd(&deg[ei[E_ + e]], 1);
}

__global__ __launch_bounds__(256) void scan_chunk(const int* __restrict__ deg,
                                                  int* __restrict__ csum, int n) {
    int base = blockIdx.x * SCH;
    int s = 0;
    for (int i = threadIdx.x; i < SCH; i += 256) {
        int idx = base + i;
        if (idx < n) s += deg[idx];
    }
    __shared__ int red[4];
    #pragma unroll
    for (int d = 1; d < 64; d <<= 1) s += __shfl_xor(s, d);
    if ((threadIdx.x & 63) == 0) red[threadIdx.x >> 6] = s;
    __syncthreads();
    if (threadIdx.x == 0) csum[blockIdx.x] = red[0] + red[1] + red[2] + red[3];
}

__global__ __launch_bounds__(1024) void scan_csum_k(const int* __restrict__ csum,
                                                    int* __restrict__ coff, int nch,
                                                    int* __restrict__ off, int n, int E_) {
    __shared__ int sm[1024];
    const int tid = threadIdx.x;
    int v = (tid < nch) ? csum[tid] : 0;
    sm[tid] = v;
    __syncthreads();
    for (int st = 1; st < 1024; st <<= 1) {
        int t = (tid >= st) ? sm[tid - st] : 0;
        __syncthreads();
        sm[tid] += t;
        __syncthreads();
    }
    if (tid < nch) coff[tid] = sm[tid] - v;   // exclusive
    if (tid == 0) off[n] = E_;                // total degree == E
}

__global__ __launch_bounds__(256) void scan_emit(const int* __restrict__ deg,
                                                 const int* __restrict__ coff,
                                                 int* __restrict__ off, int n) {
    const int base = blockIdx.x * SCH + threadIdx.x * 8;
    int vals[8]; int s = 0;
    #pragma unroll
    for (int j = 0; j < 8; j++) {
        int idx = base + j;
        vals[j] = (idx < n) ? deg[idx] : 0;
        s += vals[j];
    }
    __shared__ int ts[256];
    ts[threadIdx.x] = s;
    __syncthreads();
    for (int st = 1; st < 256; st <<= 1) {
        int t = (threadIdx.x >= st) ? ts[threadIdx.x - st] : 0;
        __syncthreads();
        ts[threadIdx.x] += t;
        __syncthreads();
    }
    int prefix = coff[blockIdx.x] + ts[threadIdx.x] - s;
    #pragma unroll
    for (int j = 0; j < 8; j++) {
        int idx = base + j;
        if (idx < n) off[idx] = prefix;
        prefix += vals[j];
    }
}

__global__ __launch_bounds__(256) void scatter_kernel(const int* __restrict__ ei,
                                                      const float* __restrict__ elen,
                                                      const int* __restrict__ off,
                                                      int* __restrict__ cur,
                                                      int* __restrict__ perm,
                                                      int* __restrict__ srcp,
                                                      float* __restrict__ Cp, int E_) {
    int e = blockIdx.x * blockDim.x + threadIdx.x;
    if (e < E_) {
        int d = ei[E_ + e];
        int p = off[d] + atomicAdd(&cur[d], 1);
        perm[p] = e;
        srcp[p] = ei[e];
        float len = elen[e];
        float c = 0.5f * (__cosf(len * (PI_F / CUTOFF)) + 1.0f);
        Cp[p] = (len <= CUTOFF && len >= 0.0f) ? c : 0.0f;
    }
}

// tnlo[t] = first node n with off[n] >= 64*t (tile ownership table)
__global__ __launch_bounds__(256) void tilebnd_kernel(const int* __restrict__ off,
                                                      int* __restrict__ tnlo,
                                                      int nN, int ntiles) {
    int t = blockIdx.x * blockDim.x + threadIdx.x;
    if (t > ntiles) return;
    if (t == ntiles) { tnlo[t] = nN; return; }
    int key = t * ET;
    int lo = 0, hi = nN + 1;
    while (lo < hi) { int mid = (lo + hi) >> 1; if (off[mid] < key) lo = mid + 1; else hi = mid; }
    tnlo[t] = lo;
}

// -------------------------------------------------------------------------
// wf_kernel — WT=128-edge tiles, 512 threads / 8 waves, one 16-col ct-tile
// per wave, 8 m-tiles per wave. Halves per-tile fixed overhead vs R18.
// Regs ~95 unified (w1f 8 + w2f 16 VGPR + acc 32 AGPR) < cap 128 at (512,4).
__global__ __launch_bounds__(512, 4) void wf_kernel(const float* __restrict__ eattr,
                                                    const float* __restrict__ em1w,
                                                    const float* __restrict__ em1b,
                                                    const float* __restrict__ em2w,
                                                    const float* __restrict__ em2b,
                                                    const int* __restrict__ perm,
                                                    const float* __restrict__ Cp,
                                                    unsigned int* __restrict__ wmsg32,
                                                    int E_) {
    __shared__ __align__(16) char U[WT * 128 + WT * 256];   // ea 16K | h 32K
    __shared__ float C_sm[WT];
    char* ea_p  = U;               // [128][64k] fp16 swizzled
    char* h_p   = U + WT * 128;    // [128][128ch] fp16 swizzled
    char* msg_b = U;               // [128] rows x 264B (33.8K), overlays ea/h

    const int tid  = threadIdx.x;
    const int wid  = tid >> 6;     // wave 0..7 -> column tile (16 ch)
    const int lane = tid & 63;
    const int l15  = lane & 15;
    const int lhi  = lane >> 4;
    const int col  = wid * 16 + l15;

    f16x8 w1f[2];
    f16x8 w2f[4];
    const float b1c = em1b[col];
    const float b2c = em2b[col];
    #pragma unroll
    for (int t = 0; t < 2; t++)
        #pragma unroll
        for (int j = 0; j < 8; j++) {
            int k = t * 32 + lhi * 8 + j;
            w1f[t][j] = (_Float16)((k < EC) ? em1w[k * NF + col] : 0.0f);
        }
    #pragma unroll
    for (int t = 0; t < 4; t++)
        #pragma unroll
        for (int j = 0; j < 8; j++) {
            int k = t * 32 + lhi * 8 + j;
            w2f[t][j] = (_Float16)em2w[k * NF + col];
        }

    const int ntiles = (E_ + WT - 1) / WT;
    for (int tile = blockIdx.x; tile < ntiles; tile += gridDim.x) {
        const int base = tile * WT;
        const int ec = min(WT, E_ - base);
        const int mmax = (ec + 15) >> 4;     // up to 8
        __syncthreads();   // prev copy done

        if (tid < WT) C_sm[tid] = (tid < ec) ? Cp[base + tid] : 0.0f;
        // stage ea: row = tid>>2 (0..127), part = tid&3, 16 k's (8 f16x2)
        {
            int row = tid >> 2, part = tid & 3;
            bool val = row < ec;
            const float* ep = eattr + (size_t)(val ? perm[base + row] : 0) * EC;
            #pragma unroll
            for (int kk = 0; kk < 16; kk += 2) {
                int k = part * 16 + kk;
                float2 v = make_float2(0.f, 0.f);
                if (val && k <= 48) v = *(const float2*)(ep + k);
                f16x2 pk;
                pk[0] = (_Float16)v.x; pk[1] = (_Float16)v.y;
                *(f16x2*)(ea_p + row * 128 + ((2 * k) ^ ((row & 7) << 4))) = pk;
            }
        }
        __syncthreads();

        // layer 1: h = ssp(ea @ em1 + b1), 8 m-tiles
        f32x4 acc[8];
        #pragma unroll
        for (int m = 0; m < 8; m++) {
            if (m < mmax) {
                f32x4 b = {b1c, b1c, b1c, b1c};
                acc[m] = b;
                const int row = m * 16 + l15;
                #pragma unroll
                for (int t1 = 0; t1 < 2; t1++) {
                    int o = row * 128 + ((t1 * 64 + lhi * 16) ^ ((row & 7) << 4));
                    f16x8 a = *(const f16x8*)(ea_p + o);
                    acc[m] = __builtin_amdgcn_mfma_f32_16x16x32_f16(a, w1f[t1], acc[m], 0, 0, 0);
                }
            }
        }
        #pragma unroll
        for (int m = 0; m < 8; m++) {
            if (m < mmax) {
                #pragma unroll
                for (int r = 0; r < 4; r++) {
                    int row = m * 16 + lhi * 4 + r;
                    *(_Float16*)(h_p + row * 256 + ((2 * col) ^ ((row & 7) << 4))) =
                        (_Float16)sspf(acc[m][r]);
                }
            }
        }
        __syncthreads();

        // layer 2: wf = h @ em2 + b2
        #pragma unroll
        for (int m = 0; m < 8; m++) {
            if (m < mmax) {
                f32x4 b = {b2c, b2c, b2c, b2c};
                acc[m] = b;
                const int row = m * 16 + l15;
                #pragma unroll
                for (int t2 = 0; t2 < 4; t2++) {
                    int o = row * 256 + ((t2 * 64 + lhi * 16) ^ ((row & 7) << 4));
                    f16x8 a = *(const f16x8*)(h_p + o);
                    acc[m] = __builtin_amdgcn_mfma_f32_16x16x32_f16(a, w2f[t2], acc[m], 0, 0, 0);
                }
            }
        }
        __syncthreads();   // h reads done; msg overlays ea/h

        #pragma unroll
        for (int m = 0; m < 8; m++) {
            if (m < mmax) {
                #pragma unroll
                for (int r = 0; r < 4; r++) {
                    int e = m * 16 + lhi * 4 + r;
                    *(_Float16*)(msg_b + e * 264 + 2 * col) =
                        (_Float16)(acc[m][r] * C_sm[e]);
                }
            }
        }
        __syncthreads();

        // coalesced LDS -> global copy (non-temporal stream)
        for (int j = tid; j < ec * 64; j += 512)
            __builtin_nontemporal_store(
                *(const unsigned int*)(msg_b + (j >> 6) * 264 + (j & 63) * 4),
                &wmsg32[(size_t)base * 64 + j]);
    }
}

// -------------------------------------------------------------------------
// red_conv — pure gather-reduce; fp16 y rows (256B), fp16 agg (R18-verified).
__global__ __launch_bounds__(256) void red_conv(const unsigned int* __restrict__ y32,
                                                const unsigned int* __restrict__ wmsg32,
                                                const int* __restrict__ srcp,
                                                const int* __restrict__ off,
                                                const int* __restrict__ tnlo,
                                                unsigned int* __restrict__ agg32,
                                                int ntiles) {
    const int wid  = threadIdx.x >> 6;
    const int lane = threadIdx.x & 63;

    for (int tile = blockIdx.x; tile < ntiles; tile += gridDim.x) {
        const int n_lo = tnlo[tile], n_hi1 = tnlo[tile + 1];
        for (int n = n_lo + wid; n < n_hi1; n += 4) {
            float2 a = make_float2(0.f, 0.f);
            int i = off[n];
            const int e1 = off[n + 1];
            for (; i + 4 <= e1; i += 4) {
                int s0 = srcp[i], s1 = srcp[i + 1], s2 = srcp[i + 2], s3 = srcp[i + 3];
                unsigned int u0 = __builtin_nontemporal_load(&wmsg32[(size_t)(i    ) * 64 + lane]);
                unsigned int u1 = __builtin_nontemporal_load(&wmsg32[(size_t)(i + 1) * 64 + lane]);
                unsigned int u2 = __builtin_nontemporal_load(&wmsg32[(size_t)(i + 2) * 64 + lane]);
                unsigned int u3 = __builtin_nontemporal_load(&wmsg32[(size_t)(i + 3) * 64 + lane]);
                unsigned int v0 = y32[(size_t)s0 * 64 + lane];
                unsigned int v1 = y32[(size_t)s1 * 64 + lane];
                unsigned int v2 = y32[(size_t)s2 * 64 + lane];
                unsigned int v3 = y32[(size_t)s3 * 64 + lane];
                f16x2 m0 = *(const f16x2*)&u0, m1 = *(const f16x2*)&u1;
                f16x2 m2 = *(const f16x2*)&u2, m3 = *(const f16x2*)&u3;
                f16x2 q0 = *(const f16x2*)&v0, q1 = *(const f16x2*)&v1;
                f16x2 q2 = *(const f16x2*)&v2, q3 = *(const f16x2*)&v3;
                a.x = fmaf((float)m0[0], (float)q0[0], a.x); a.y = fmaf((float)m0[1], (float)q0[1], a.y);
                a.x = fmaf((float)m1[0], (float)q1[0], a.x); a.y = fmaf((float)m1[1], (float)q1[1], a.y);
                a.x = fmaf((float)m2[0], (float)q2[0], a.x); a.y = fmaf((float)m2[1], (float)q2[1], a.y);
                a.x = fmaf((float)m3[0], (float)q3[0], a.x); a.y = fmaf((float)m3[1], (float)q3[1], a.y);
            }
            for (; i < e1; i++) {
                unsigned int u = __builtin_nontemporal_load(&wmsg32[(size_t)i * 64 + lane]);
                unsigned int v = y32[(size_t)srcp[i] * 64 + lane];
                f16x2 mp = *(const f16x2*)&u;
                f16x2 qv = *(const f16x2*)&v;
                a.x = fmaf((float)mp[0], (float)qv[0], a.x);
                a.y = fmaf((float)mp[1], (float)qv[1], a.y);
            }
            f16x2 o; o[0] = (_Float16)a.x; o[1] = (_Float16)a.y;
            agg32[(size_t)n * 64 + lane] = *(const unsigned int*)&o;
        }
    }
}

// -------------------------------------------------------------------------
extern "C" void kernel_launch(void* const* d_in, const int* in_sizes, int n_in,
                              void* d_out, int out_size, void* d_ws, size_t ws_size,
                              hipStream_t stream) {
    const float* tt    = (const float*)d_in[0];
    const float* xx    = (const float*)d_in[1];
    const int*   ei    = (const int*)d_in[2];
    const float* elen  = (const float*)d_in[3];
    const float* eattr = (const float*)d_in[4];
    const float* em1w  = (const float*)d_in[5];
    const float* em1b  = (const float*)d_in[6];
    const float* em2w  = (const float*)d_in[7];
    const float* em2b  = (const float*)d_in[8];
    const float* c1m1w = (const float*)d_in[9];
    const float* c1m2w = (const float*)d_in[10];
    const float* c1m2b = (const float*)d_in[11];
    const float* c2m1w = (const float*)d_in[12];
    const float* c2m2w = (const float*)d_in[13];
    const float* c2m2b = (const float*)d_in[14];
    const float* tew   = (const float*)d_in[15];
    const float* teb   = (const float*)d_in[16];
    const float* linw  = (const float*)d_in[17];
    const float* linb  = (const float*)d_in[18];

    const int n  = in_sizes[0];
    const int E_ = in_sizes[2] / 2;
    const int ntiles = (E_ + ET - 1) / ET;
    const int gtiles = (n + 63) >> 6;
    const int nch = (n + SCH - 1) / SCH;
    float* out = (float*)d_out;

    // ws layout: fp16 node buffers (3 x NB halfs) then CSR ints + wmsg.
    const size_t NB = (size_t)n * NF;
    _Float16* B0h = (_Float16*)d_ws;   // y1 / y2 / x3   (fp16)
    _Float16* B1h = B0h + NB;          // agg            (fp16)
    _Float16* B2h = B1h + NB;          // emb/t/x_mid    (fp16)
    int* off  = (int*)(B2h + NB);      // n+1
    int* perm = off + (n + 1);         // E
    int* deg  = perm + E_;             // n
    int* cur  = deg + n;               // n
    int* srcp = cur + n;               // E
    int* tnlo = srcp + E_;             // ntiles+1
    int* csum = tnlo + ntiles + 1;     // nch
    int* coff = csum + nch;            // nch
    float* Cp = (float*)(coff + nch);  // E
    unsigned int* wmsg32 = (unsigned int*)(Cp + E_);   // E*64 u32

    // ---- CSR build (multi-block scan) + ownership table
    hipMemsetAsync(deg, 0, (size_t)2 * n * sizeof(int), stream);
    deg_kernel<<<(E_ + 255) / 256, 256, 0, stream>>>(ei, deg, E_);
    scan_chunk<<<nch, 256, 0, stream>>>(deg, csum, n);
    scan_csum_k<<<1, 1024, 0, stream>>>(csum, coff, nch, off, n, E_);
    scan_emit<<<nch, 256, 0, stream>>>(deg, coff, off, n);
    scatter_kernel<<<(E_ + 255) / 256, 256, 0, stream>>>(ei, elen, off, cur,
                                                         perm, srcp, Cp, E_);
    tilebnd_kernel<<<(ntiles + 256) / 256, 256, 0, stream>>>(off, tnlo, n, ntiles);

    // emb -> B2h ; t = swish_emb @ te_w + te_b -> B2h (in-place safe)
    emb_kernel<<<(n * 64 + 255) / 256, 256, 0, stream>>>(tt, B2h, n);
    mfma_gemm<3, 1, 1><<<gtiles, 256, 0, stream>>>(B2h, tew, teb, nullptr, B2h, n);

    // msg = Wf*C (conv-invariant) computed ONCE; WT=128-edge tiles
    wf_kernel<<<1280, 512, 0, stream>>>(eattr, em1w, em1b, em2w, em2b,
                                        perm, Cp, wmsg32, E_);

    // y1 = xx @ c1_m1w -> B0h   (A = f32 input)
    mfma_gemm<0, 0, 1><<<gtiles, 256, 0, stream>>>(xx, c1m1w, nullptr, nullptr, B0h, n);

    // conv1 -> B1h
    red_conv<<<4096, 256, 0, stream>>>((const unsigned int*)B0h, wmsg32, srcp,
                                       off, tnlo, (unsigned int*)B1h, ntiles);

    // x_mid = ssp(agg @ c1_m2w + b + t) -> B2h (extra==out elementwise-safe)
    mfma_gemm<2, 1, 1><<<gtiles, 256, 0, stream>>>(B1h, c1m2w, c1m2b, B2h, B2h, n);

    // y2 = x_mid @ c2_m1w -> B0h
    mfma_gemm<0, 1, 1><<<gtiles, 256, 0, stream>>>(B2h, c2m1w, nullptr, nullptr, B0h, n);

    // conv2 -> B1h
    red_conv<<<4096, 256, 0, stream>>>((const unsigned int*)B0h, wmsg32, srcp,
                                       off, tnlo, (unsigned int*)B1h, ntiles);

    // x3 = ssp(agg @ c2_m2w + b) -> B0h ; out = ssp(x3 @ lin_w + b) -> d_out (f32)
    mfma_gemm<1, 1, 1><<<gtiles, 256, 0, stream>>>(B1h, c2m2w, c2m2b, nullptr, B0h, n);
    mfma_gemm<1, 1, 0><<<gtiles, 256, 0, stream>>>(B0h, linw, linb, nullptr, out, n);
}